// Round 14
// baseline (2936.133 us; speedup 1.0000x reference)
//
#include <hip/hip_runtime.h>
#include <hip/hip_bf16.h>
#include <math.h>

#define H 8
#define DK 64
#define DIM 512
#define DFF 2048
#define DEPTH 8
#define VOCAB 32000
#define NTOK 2048

typedef float f32x4 __attribute__((ext_vector_type(4)));
typedef short bf16x8 __attribute__((ext_vector_type(8)));

static __device__ __forceinline__ unsigned short f2bf(float f) {
    unsigned u = __float_as_uint(f);
    return (unsigned short)((u + 0x7FFFu + ((u >> 16) & 1u)) >> 16);
}

#define GLL(src, dst) __builtin_amdgcn_global_load_lds( \
    (const __attribute__((address_space(1))) unsigned int*)(src), \
    (__attribute__((address_space(3))) unsigned int*)(dst), 16, 0, 0)

// load per-row LN stats (8 partial sum/sumsq pairs) -> mean + inv; identity if stats==null
static __device__ __forceinline__ void load_ln_stats(
    const float* __restrict__ stats, int base, int rows,
    float* Lm, float* Li, int tid, int nthr)
{
    for (int r = tid; r < rows; r += nthr) {
        float m = 0.f, inv = 1.f;
        if (stats) {
            const float* s = stats + (size_t)(base + r) * 16;
            float sum = 0.f, sq = 0.f;
#pragma unroll
            for (int b = 0; b < 8; b++) { sum += s[b * 2]; sq += s[b * 2 + 1]; }
            m = sum * (1.f / 512.f);
            float v = sq * (1.f / 512.f) - m * m;
            inv = 1.f / sqrtf(v + 1e-5f);
        }
        Lm[r] = m; Li[r] = inv;
    }
}

// ---------------- embed ----------------
__global__ void embed_kernel(const float* __restrict__ emb, const int* __restrict__ tok,
                             const float* __restrict__ pos, const int* __restrict__ pidx,
                             float* __restrict__ out, int n4) {
    int idx = blockIdx.x * blockDim.x + threadIdx.x;
    if (idx >= n4) return;
    int i = idx >> 7, d = idx & 127;
    float4 a = ((const float4*)emb)[(size_t)tok[i] * 128 + d];
    float4 b = ((const float4*)pos)[(size_t)pidx[i] * 128 + d];
    ((float4*)out)[idx] = make_float4(a.x + b.x, a.y + b.y, a.z + b.z, a.w + b.w);
}

// ---------------- batched weight convert+transpose ----------------
struct WD { const float* src; unsigned short* dst; int K; int N; int t0; int pad; };
struct WTab { WD d[12]; };

__global__ __launch_bounds__(256) void wconv_all(WTab tab) {
    __shared__ float t[32][33];
    const int bid = blockIdx.x;
    int w = 0;
#pragma unroll
    for (int i = 1; i < 12; i++) if (bid >= tab.d[i].t0) w = i;
    const float* W = tab.d[w].src;
    unsigned short* Wt = tab.d[w].dst;
    const int K = tab.d[w].K, N = tab.d[w].N;
    const int lt = bid - tab.d[w].t0;
    const int txc = N >> 5;
    const int n0 = (lt % txc) << 5, k0 = (lt / txc) << 5;
    const int tid = threadIdx.x;
    const int tx = tid & 31, ty = tid >> 5;
#pragma unroll
    for (int i = 0; i < 32; i += 8)
        t[ty + i][tx] = W[(size_t)(k0 + ty + i) * N + n0 + tx];
    __syncthreads();
#pragma unroll
    for (int i = 0; i < 32; i += 8)
        Wt[(size_t)(n0 + ty + i) * K + k0 + tx] = f2bf(t[tx][ty + i]);
}

// ---------------- gemm_rb: C = LN(T) @ Bt^T, double-buffered ----------------
// EPI 1: relu->bf16; 3: bf16.  BN = 64.
template<int EPI>
__global__ __launch_bounds__(256) void gemm_rb(
    const float* __restrict__ Tf,
    const float* __restrict__ stats,
    const unsigned short* __restrict__ Bt,
    unsigned short* __restrict__ Cb,
    int M, int N, int K)
{
    constexpr int BN = 64, JN = 2;
    __shared__ __align__(16) unsigned short Asm[2][128 * 64];
    __shared__ __align__(16) unsigned short Bsm[2][BN * 64];
    __shared__ float Lm[128], Li[128];
    const int tid = threadIdx.x;
    const int lane = tid & 63, wid = tid >> 6;
    const int m0 = blockIdx.y * 128, n0 = blockIdx.x * BN;
    const int wm = (wid >> 1) * 64, wn = (wid & 1) * (BN / 2);
    const int NK = K >> 6;

    float4 ar0[4], ar1[4];
    auto loadA = [&](int k0) {
#pragma unroll
        for (int it = 0; it < 4; it++) {
            int q = it * 256 + tid;
            int row = q >> 3;
            int cs = q & 7;
            const float* s = Tf + (size_t)(m0 + row) * K + k0 + cs * 8;
            ar0[it] = *(const float4*)s;
            ar1[it] = *(const float4*)(s + 4);
        }
    };
    auto storeA = [&](int buf) {
#pragma unroll
        for (int it = 0; it < 4; it++) {
            int q = it * 256 + tid;
            int row = q >> 3;
            int cs = q & 7;
            float m = Lm[row], iv = Li[row];
            unsigned short c8[8];
            c8[0] = f2bf((ar0[it].x - m) * iv); c8[1] = f2bf((ar0[it].y - m) * iv);
            c8[2] = f2bf((ar0[it].z - m) * iv); c8[3] = f2bf((ar0[it].w - m) * iv);
            c8[4] = f2bf((ar1[it].x - m) * iv); c8[5] = f2bf((ar1[it].y - m) * iv);
            c8[6] = f2bf((ar1[it].z - m) * iv); c8[7] = f2bf((ar1[it].w - m) * iv);
            *(bf16x8*)&Asm[buf][row * 64 + ((cs ^ (row & 7)) * 8)] = *(bf16x8*)c8;
        }
    };
    auto stageB = [&](int k0, int buf) {
#pragma unroll
        for (int it = 0; it < BN / 32; it++) {
            int q = it * 256 + tid;
            int row = q >> 3;
            int cs = (q & 7) ^ (row & 7);
            GLL(Bt + (size_t)(n0 + row) * K + k0 + cs * 8, &Bsm[buf][q * 8]);
        }
    };

    load_ln_stats(stats, m0, 128, Lm, Li, tid, 256);
    loadA(0);
    __syncthreads();
    storeA(0);
    stageB(0, 0);

    f32x4 acc[4][JN];
#pragma unroll
    for (int i = 0; i < 4; i++)
#pragma unroll
        for (int j = 0; j < JN; j++) acc[i][j] = (f32x4){0.f, 0.f, 0.f, 0.f};

    for (int kt = 0; kt < NK; kt++) {
        __syncthreads();
        const int cur = kt & 1, nxt = (kt + 1) & 1;
        if (kt + 1 < NK) {
            stageB((kt + 1) << 6, nxt);
            loadA((kt + 1) << 6);
        }
#pragma unroll
        for (int kk = 0; kk < 2; kk++) {
            bf16x8 af[4], bfr[JN];
#pragma unroll
            for (int i = 0; i < 4; i++) {
                int rowA = wm + i * 16 + (lane & 15);
                int ca = (kk * 4 + (lane >> 4)) ^ (rowA & 7);
                af[i] = *(const bf16x8*)&Asm[cur][rowA * 64 + ca * 8];
            }
#pragma unroll
            for (int j = 0; j < JN; j++) {
                int rowB = wn + j * 16 + (lane & 15);
                int cb = (kk * 4 + (lane >> 4)) ^ (rowB & 7);
                bfr[j] = *(const bf16x8*)&Bsm[cur][rowB * 64 + cb * 8];
            }
#pragma unroll
            for (int i = 0; i < 4; i++)
#pragma unroll
                for (int j = 0; j < JN; j++)
                    acc[i][j] = __builtin_amdgcn_mfma_f32_16x16x32_bf16(af[i], bfr[j], acc[i][j], 0, 0, 0);
        }
        if (kt + 1 < NK) storeA(nxt);
    }
#pragma unroll
    for (int i = 0; i < 4; i++)
#pragma unroll
        for (int j = 0; j < JN; j++)
#pragma unroll
            for (int r = 0; r < 4; r++) {
                int row = m0 + wm + i * 16 + (lane >> 4) * 4 + r;
                int col = n0 + wn + j * 16 + (lane & 15);
                size_t idx = (size_t)row * N + col;
                float v = acc[i][j][r];
                if (EPI == 1) Cb[idx] = f2bf(fmaxf(v, 0.f));
                if (EPI == 3) Cb[idx] = f2bf(v);
            }
}

// ---------------- gemm_bb: Tout = LN(Tin) + A @ Bt^T, double-buffered ----------------
__global__ __launch_bounds__(256) void gemm_bb(
    const unsigned short* __restrict__ A,
    const unsigned short* __restrict__ Bt,
    const float* __restrict__ Tin,
    const float* __restrict__ statsIn,
    float* __restrict__ Tout,
    float* __restrict__ statsOut,
    int M, int K)
{
    __shared__ __align__(16) unsigned short Asm[2][32 * 64];
    __shared__ __align__(16) unsigned short Bsm[2][64 * 64];
    __shared__ float Lm[32], Li[32];
    __shared__ float sredS[4][32], sredQ[4][32];
    const int tid = threadIdx.x;
    const int lane = tid & 63, wid = tid >> 6;
    const int nb = blockIdx.x;
    const int m0 = blockIdx.y * 32, n0 = nb * 64;
    const int wn = wid * 16;
    const int NK = K >> 6;

    auto stage = [&](int k0, int buf) {
        {
            int q = tid;
            int row = q >> 3;
            int cs = (q & 7) ^ (row & 7);
            GLL(A + (size_t)(m0 + row) * K + k0 + cs * 8, &Asm[buf][q * 8]);
        }
#pragma unroll
        for (int it = 0; it < 2; it++) {
            int q = it * 256 + tid;
            int row = q >> 3;
            int cs = (q & 7) ^ (row & 7);
            GLL(Bt + (size_t)(n0 + row) * K + k0 + cs * 8, &Bsm[buf][q * 8]);
        }
    };

    load_ln_stats(statsIn, m0, 32, Lm, Li, tid, 256);
    stage(0, 0);

    f32x4 acc[2];
#pragma unroll
    for (int i = 0; i < 2; i++) acc[i] = (f32x4){0.f, 0.f, 0.f, 0.f};

    for (int kt = 0; kt < NK; kt++) {
        __syncthreads();
        const int cur = kt & 1, nxt = (kt + 1) & 1;
        if (kt + 1 < NK) stage((kt + 1) << 6, nxt);
#pragma unroll
        for (int kd = 0; kd < 2; kd++) {
            int rowB = wn + (lane & 15);
            int cb = (kd * 4 + (lane >> 4)) ^ (rowB & 7);
            bf16x8 bfr = *(const bf16x8*)&Bsm[cur][rowB * 64 + cb * 8];
#pragma unroll
            for (int i = 0; i < 2; i++) {
                int rowA = i * 16 + (lane & 15);
                int ca = (kd * 4 + (lane >> 4)) ^ (rowA & 7);
                bf16x8 af = *(const bf16x8*)&Asm[cur][rowA * 64 + ca * 8];
                acc[i] = __builtin_amdgcn_mfma_f32_16x16x32_bf16(af, bfr, acc[i], 0, 0, 0);
            }
        }
    }
#pragma unroll
    for (int i = 0; i < 2; i++) {
#pragma unroll
        for (int r = 0; r < 4; r++) {
            int rl = i * 16 + (lane >> 4) * 4 + r;
            int row = m0 + rl;
            int col = n0 + wn + (lane & 15);
            size_t idx = (size_t)row * DIM + col;
            float rv = (Tin[idx] - Lm[rl]) * Li[rl];
            float v = acc[i][r] + rv;
            Tout[idx] = v;
            float s = v, q = v * v;
            s += __shfl_xor(s, 1); s += __shfl_xor(s, 2);
            s += __shfl_xor(s, 4); s += __shfl_xor(s, 8);
            q += __shfl_xor(q, 1); q += __shfl_xor(q, 2);
            q += __shfl_xor(q, 4); q += __shfl_xor(q, 8);
            if ((lane & 15) == 0) { sredS[wid][rl] = s; sredQ[wid][rl] = q; }
        }
    }
    __syncthreads();
    if (tid < 32) {
        int row = tid;
        float s = sredS[0][row] + sredS[1][row] + sredS[2][row] + sredS[3][row];
        float q = sredQ[0][row] + sredQ[1][row] + sredQ[2][row] + sredQ[3][row];
        statsOut[(size_t)(m0 + row) * 16 + nb * 2] = s;
        statsOut[(size_t)(m0 + row) * 16 + nb * 2 + 1] = q;
    }
}

// ---------------- attention phase 2: split keys across wave pairs ----------------
template<int CAUSAL>
static __device__ __forceinline__ void attn_phase2_split(
    const unsigned short* Qs, const unsigned short* Ks, const unsigned short* Vt,
    unsigned short* Psw, float* dumpf,
    int qh, int wid, int lane, int tok0, int h,
    unsigned short* __restrict__ O)
{
    const int qg = wid & 3, kh = wid >> 2;
    bf16x8 qa[2];
#pragma unroll
    for (int kd = 0; kd < 2; kd++) {
        int qr = qg * 16 + (lane & 15);
        int ch = (kd * 4 + (lane >> 4)) ^ (qr & 7);
        qa[kd] = *(const bf16x8*)&Qs[qr * 64 + ch * 8];
    }
    int jn, kcn;
    if (!CAUSAL)      { jn = 4; kcn = 2; }
    else if (kh > qh) { jn = 0; kcn = 0; }
    else if (kh < qh) { jn = 4; kcn = 2; }
    else              { kcn = (qg >> 1) + 1; jn = kcn * 2; }

    float zr[4] = {0.f, 0.f, 0.f, 0.f};
    f32x4 oacc[4];
#pragma unroll
    for (int dt = 0; dt < 4; dt++) oacc[dt] = (f32x4){0.f, 0.f, 0.f, 0.f};

    if (jn > 0) {
        f32x4 sacc[4];
#pragma unroll
        for (int j = 0; j < 4; j++) sacc[j] = (f32x4){0.f, 0.f, 0.f, 0.f};
#pragma unroll 2
        for (int kd = 0; kd < 2; kd++) {
            for (int jj = 0; jj < jn; jj++) {
                int kr = kh * 64 + jj * 16 + (lane & 15);
                int ch = (kd * 4 + (lane >> 4)) ^ (kr & 7);
                bf16x8 kf = *(const bf16x8*)&Ks[kr * 64 + ch * 8];
                sacc[jj] = __builtin_amdgcn_mfma_f32_16x16x32_bf16(qa[kd], kf, sacc[jj], 0, 0, 0);
            }
        }
        int qbase = qh * 64 + qg * 16 + (lane >> 4) * 4;
        for (int jj = 0; jj < jn; jj++) {
            int kcol = kh * 64 + jj * 16 + (lane & 15);
#pragma unroll
            for (int rr = 0; rr < 4; rr++) {
                float p = __expf(sacc[jj][rr] * 0.125f);
                if (CAUSAL && kcol > qbase + rr) p = 0.f;
                zr[rr] += p;
                int prow = (lane >> 4) * 4 + rr;
                int ch = ((jj * 2 + ((lane & 15) >> 3)) ^ (prow & 7));
                Psw[prow * 64 + ch * 8 + (lane & 7)] = f2bf(p);
            }
        }
        for (int kcl = 0; kcl < kcn; kcl++) {
            bf16x8 pa;
            {
                int prow = lane & 15;
                int ch = (kcl * 4 + (lane >> 4)) ^ (prow & 7);
                pa = *(const bf16x8*)&Psw[prow * 64 + ch * 8];
            }
            int kcg = kh * 2 + kcl;
#pragma unroll
            for (int dt = 0; dt < 4; dt++) {
                int d = dt * 16 + (lane & 15);
                bf16x8 vf = *(const bf16x8*)&Vt[d * 132 + (kcg * 4 + (lane >> 4)) * 8];
                oacc[dt] = __builtin_amdgcn_mfma_f32_16x16x32_bf16(pa, vf, oacc[dt], 0, 0, 0);
            }
        }
    }
    __syncthreads();
    if (kh == 1) {
        float* dst = dumpf + (size_t)(qg * 64 + lane) * 20;
#pragma unroll
        for (int dt = 0; dt < 4; dt++)
#pragma unroll
            for (int rr = 0; rr < 4; rr++) dst[dt * 4 + rr] = oacc[dt][rr];
#pragma unroll
        for (int rr = 0; rr < 4; rr++) dst[16 + rr] = zr[rr];
    }
    __syncthreads();
    if (kh == 0) {
        const float* src = dumpf + (size_t)(qg * 64 + lane) * 20;
#pragma unroll
        for (int dt = 0; dt < 4; dt++)
#pragma unroll
            for (int rr = 0; rr < 4; rr++) oacc[dt][rr] += src[dt * 4 + rr];
#pragma unroll
        for (int rr = 0; rr < 4; rr++) {
            float z = zr[rr] + src[16 + rr];
            z += __shfl_xor(z, 1); z += __shfl_xor(z, 2);
            z += __shfl_xor(z, 4); z += __shfl_xor(z, 8);
            zr[rr] = 1.f / (z + 1e-9f);
        }
#pragma unroll
        for (int dt = 0; dt < 4; dt++)
#pragma unroll
            for (int rr = 0; rr < 4; rr++) {
                int qrow = tok0 + qh * 64 + qg * 16 + (lane >> 4) * 4 + rr;
                O[(size_t)qrow * DIM + h * 64 + dt * 16 + (lane & 15)] =
                    f2bf(oacc[dt][rr] * zr[rr]);
            }
    }
}

// ---------------- fused QKV-GEMM + self-attention: 256 blocks (b,h,qhalf) ----------------
// async Tf loads overlap MFMA; Q cols computed only by own-half waves.
template<int CAUSAL>
__global__ __launch_bounds__(512) void fused_attn(
    const float* __restrict__ Tf,
    const float* __restrict__ stats,
    const float* __restrict__ pos,
    const float* __restrict__ trow,
    const unsigned short* __restrict__ WqkvT,
    unsigned short* __restrict__ O)
{
    __shared__ __align__(16) unsigned short smem[28928];
    __shared__ float LmA[128], LiA[128];
    unsigned short* Asm = smem;
    unsigned short* Bsm = smem + 8192;
    unsigned short* Qs  = smem;
    unsigned short* Ks  = smem + 4096;
    unsigned short* Vt  = smem + 12288;
    float* dumpf = (float*)smem;
    const int tid = threadIdx.x;
    const int lane = tid & 63, wid = tid >> 6;
    unsigned short* Psw = smem + 20736 + wid * 1024;
    const int blk = blockIdx.x;
    const int qh = blk & 1, h = (blk >> 1) & 7, b = blk >> 4;
    const int tok0 = b * 128;
    const int wr = wid * 16;
    const int cmin = ((wid >> 2) == qh) ? 0 : 4;   // skip Q cols for other-half waves

    float4 ua[2], ub[2];
    auto loadT = [&](int k0) {
#pragma unroll
        for (int it = 0; it < 2; it++) {
            int q = it * 512 + tid;
            int row = q >> 3;
            int cs = q & 7;
            const float* s = Tf + (size_t)(tok0 + row) * 512 + k0 + cs * 8;
            ua[it] = *(const float4*)s;
            ub[it] = *(const float4*)(s + 4);
        }
    };
    auto storeT = [&](int k0) {
#pragma unroll
        for (int it = 0; it < 2; it++) {
            int q = it * 512 + tid;
            int row = q >> 3;
            int cs = q & 7;
            const float* pp = pos + (size_t)row * 512 + k0 + cs * 8;
            const float* tt = trow + k0 + cs * 8;
            float4 p0 = *(const float4*)pp, p1 = *(const float4*)(pp + 4);
            float4 t0 = *(const float4*)tt, t1 = *(const float4*)(tt + 4);
            float m = LmA[row], iv = LiA[row];
            unsigned short c8[8];
            c8[0] = f2bf((ua[it].x - m) * iv + p0.x + t0.x);
            c8[1] = f2bf((ua[it].y - m) * iv + p0.y + t0.y);
            c8[2] = f2bf((ua[it].z - m) * iv + p0.z + t0.z);
            c8[3] = f2bf((ua[it].w - m) * iv + p0.w + t0.w);
            c8[4] = f2bf((ub[it].x - m) * iv + p1.x + t1.x);
            c8[5] = f2bf((ub[it].y - m) * iv + p1.y + t1.y);
            c8[6] = f2bf((ub[it].z - m) * iv + p1.z + t1.z);
            c8[7] = f2bf((ub[it].w - m) * iv + p1.w + t1.w);
            *(bf16x8*)&Asm[row * 64 + ((cs ^ (row & 7)) * 8)] = *(bf16x8*)c8;
        }
    };

    loadT(0);
    load_ln_stats(stats, tok0, 128, LmA, LiA, tid, 512);
    __syncthreads();

    f32x4 acc[12];
#pragma unroll
    for (int c = 0; c < 12; c++) acc[c] = (f32x4){0.f, 0.f, 0.f, 0.f};

    for (int k0 = 0; k0 < 512; k0 += 64) {
        if (k0) __syncthreads();
        storeT(k0);
#pragma unroll
        for (int it = 0; it < 3; it++) {
            int q = it * 512 + wid * 64 + lane;
            int r = q >> 3;
            int cs = (q & 7) ^ (r & 7);
            int srow = (r < 64) ? (h * 64 + r)
                     : (r < 128) ? (512 + h * 64 + (r - 64))
                                 : (1024 + h * 64 + (r - 128));
            GLL(WqkvT + (size_t)srow * 512 + k0 + cs * 8, &Bsm[(it * 512 + wid * 64) * 8]);
        }
        __syncthreads();
        if (k0 + 64 < 512) loadT(k0 + 64);
#pragma unroll
        for (int kk = 0; kk < 2; kk++) {
            int rowA = wr + (lane & 15);
            int ca = (kk * 4 + (lane >> 4)) ^ (rowA & 7);
            bf16x8 af = *(const bf16x8*)&Asm[rowA * 64 + ca * 8];
            for (int c = cmin; c < 12; c++) {
                int rowB = c * 16 + (lane & 15);
                int cb = (kk * 4 + (lane >> 4)) ^ (rowB & 7);
                bf16x8 bfr = *(const bf16x8*)&Bsm[rowB * 64 + cb * 8];
                acc[c] = __builtin_amdgcn_mfma_f32_16x16x32_bf16(af, bfr, acc[c], 0, 0, 0);
            }
        }
    }
    __syncthreads();
#pragma unroll
    for (int c = 0; c < 12; c++)
#pragma unroll
        for (int r = 0; r < 4; r++) {
            int token = wr + (lane >> 4) * 4 + r;
            int col = (c & 3) * 16 + (lane & 15);
            unsigned short v = f2bf(acc[c][r]);
            if (c < 4) {
                int tl = token - qh * 64;
                if (tl >= 0 && tl < 64)
                    Qs[tl * 64 + (((col >> 3) ^ (tl & 7)) * 8) + (col & 7)] = v;
            } else if (c < 8) {
                Ks[token * 64 + (((col >> 3) ^ (token & 7)) * 8) + (col & 7)] = v;
            } else {
                Vt[col * 132 + token] = v;
            }
        }
    __syncthreads();
    attn_phase2_split<CAUSAL>(Qs, Ks, Vt, Psw, dumpf, qh, wid, lane, tok0, h, O);
}

// ---------------- fused Q-GEMM + cross-attention: 256 blocks (b,h,qhalf) ----------------
__global__ __launch_bounds__(512) void fused_xattn(
    const float* __restrict__ Tf,
    const float* __restrict__ stats,
    const float* __restrict__ pos,
    const float* __restrict__ trow,
    const unsigned short* __restrict__ WqT,
    const unsigned short* __restrict__ kvx,
    unsigned short* __restrict__ O)
{
    __shared__ __align__(16) unsigned short smem[28928];
    __shared__ float LmA[64], LiA[64];
    unsigned short* Qs  = smem;
    unsigned short* Ks  = smem + 4096;
    unsigned short* Vt  = smem + 12288;
    unsigned short* Asm = smem + 20736;
    unsigned short* Bsm = smem + 24832;
    float* dumpf = (float*)smem;
    const int tid = threadIdx.x;
    const int lane = tid & 63, wid = tid >> 6;
    unsigned short* Psw = smem + 20736 + wid * 1024;
    const int blk = blockIdx.x;
    const int qh = blk & 1, h = (blk >> 1) & 7, b = blk >> 4;
    const int tok0 = b * 128;

    float4 ua[2], ub[2];
    auto loadT = [&](int k0) {
#pragma unroll
        for (int it = 0; it < 2; it++) {
            int q = it * 256 + tid;
            int row = q >> 3;
            int cs = q & 7;
            const float* s = Tf + (size_t)(tok0 + qh * 64 + row) * 512 + k0 + cs * 8;
            ua[it] = *(const float4*)s;
            ub[it] = *(const float4*)(s + 4);
        }
    };
    auto storeT = [&](int k0) {
#pragma unroll
        for (int it = 0; it < 2; it++) {
            int q = it * 256 + tid;
            int row = q >> 3;
            int cs = q & 7;
            const float* pp = pos + (size_t)(qh * 64 + row) * 512 + k0 + cs * 8;
            const float* tt = trow + k0 + cs * 8;
            float4 p0 = *(const float4*)pp, p1 = *(const float4*)(pp + 4);
            float4 t0 = *(const float4*)tt, t1 = *(const float4*)(tt + 4);
            float m = LmA[row], iv = LiA[row];
            unsigned short c8[8];
            c8[0] = f2bf((ua[it].x - m) * iv + p0.x + t0.x);
            c8[1] = f2bf((ua[it].y - m) * iv + p0.y + t0.y);
            c8[2] = f2bf((ua[it].z - m) * iv + p0.z + t0.z);
            c8[3] = f2bf((ua[it].w - m) * iv + p0.w + t0.w);
            c8[4] = f2bf((ub[it].x - m) * iv + p1.x + t1.x);
            c8[5] = f2bf((ub[it].y - m) * iv + p1.y + t1.y);
            c8[6] = f2bf((ub[it].z - m) * iv + p1.z + t1.z);
            c8[7] = f2bf((ub[it].w - m) * iv + p1.w + t1.w);
            *(bf16x8*)&Asm[row * 64 + ((cs ^ (row & 7)) * 8)] = *(bf16x8*)c8;
        }
    };

    if (tid < 256) loadT(0);
    load_ln_stats(stats, tok0 + qh * 64, 64, LmA, LiA, tid, 512);

    if (wid >= 4) {
        int st = tid - 256;
        int r = st >> 1, c0 = (st & 1) * 4;
        const unsigned short* Kg = kvx + (size_t)(tok0 + r) * 1024 + h * 64;
        const unsigned short* Vg = Kg + 512;
#pragma unroll
        for (int c = c0; c < c0 + 4; c++) {
            bf16x8 kv = *(const bf16x8*)&Kg[c * 8];
            *(bf16x8*)&Ks[r * 64 + ((c ^ (r & 7)) * 8)] = kv;
            bf16x8 vv = *(const bf16x8*)&Vg[c * 8];
#pragma unroll
            for (int j = 0; j < 8; j++)
                Vt[(c * 8 + j) * 132 + r] = (unsigned short)vv[j];
        }
    }
    __syncthreads();

    f32x4 acc[4];
#pragma unroll
    for (int c = 0; c < 4; c++) acc[c] = (f32x4){0.f, 0.f, 0.f, 0.f};

    for (int k0 = 0; k0 < 512; k0 += 64) {
        if (k0) __syncthreads();
        if (tid < 256) {
            storeT(k0);
#pragma unroll
            for (int it = 0; it < 2; it++) {
                int q = it * 256 + tid;
                int r = q >> 3;
                int cs = (q & 7) ^ (r & 7);
                GLL(WqT + (size_t)(h * 64 + r) * 512 + k0 + cs * 8, &Bsm[q * 8]);
            }
        }
        __syncthreads();
        if (tid < 256 && k0 + 64 < 512) loadT(k0 + 64);
        if (wid < 4) {
#pragma unroll
            for (int kk = 0; kk < 2; kk++) {
                int rowA = wid * 16 + (lane & 15);
                int ca = (kk * 4 + (lane >> 4)) ^ (rowA & 7);
                bf16x8 af = *(const bf16x8*)&Asm[rowA * 64 + ca * 8];
#pragma unroll
                for (int c = 0; c < 4; c++) {
                    int rowB = c * 16 + (lane & 15);
                    int cb = (kk * 4 + (lane >> 4)) ^ (rowB & 7);
                    bf16x8 bfr = *(const bf16x8*)&Bsm[rowB * 64 + cb * 8];
                    acc[c] = __builtin_amdgcn_mfma_f32_16x16x32_bf16(af, bfr, acc[c], 0, 0, 0);
                }
            }
        }
    }
    __syncthreads();
    if (wid < 4) {
#pragma unroll
        for (int c = 0; c < 4; c++)
#pragma unroll
            for (int r = 0; r < 4; r++) {
                int tl = wid * 16 + (lane >> 4) * 4 + r;
                int col = c * 16 + (lane & 15);
                Qs[tl * 64 + (((col >> 3) ^ (tl & 7)) * 8) + (col & 7)] = f2bf(acc[c][r]);
            }
    }
    __syncthreads();
    attn_phase2_split<0>(Qs, Ks, Vt, Psw, dumpf, qh, wid, lane, tok0, h, O);
}

// ---------------- ln finalize: xb = bf16(LN(T)) using stats ----------------
__global__ __launch_bounds__(64) void ln_fin(const float* __restrict__ T,
                                             const float* __restrict__ stats,
                                             unsigned short* __restrict__ outb) {
    const int row = blockIdx.x, lane = threadIdx.x;
    const float* st = stats + (size_t)row * 16;
    float sum = 0.f, sq = 0.f;
#pragma unroll
    for (int b = 0; b < 8; b++) { sum += st[b * 2]; sq += st[b * 2 + 1]; }
    float m = sum * (1.f / 512.f);
    float v = sq * (1.f / 512.f) - m * m;
    float inv = 1.f / sqrtf(v + 1e-5f);
    const float* p = T + (size_t)row * DIM;
    unsigned short* qb = outb + (size_t)row * DIM;
#pragma unroll
    for (int i = 0; i < 8; i++)
        qb[lane + i * 64] = f2bf((p[lane + i * 64] - m) * inv);
}

// ---------------- generator: 256x128 tile, XCD-swizzled, two-pass, async-A ----------------
template<int PASS>
__global__ __launch_bounds__(512) void gemm_gen(
    const unsigned short* __restrict__ Ab,
    const unsigned short* __restrict__ Bt,
    float* __restrict__ Out,
    float* __restrict__ pm,
    float* __restrict__ psum,
    const float* __restrict__ lse)
{
    __shared__ __align__(16) unsigned short Asm[256 * 64];
    __shared__ __align__(16) unsigned short Bsm[128 * 64];
    __shared__ float pml[8][64];
    __shared__ float psl[8][64];
    __shared__ float lsh[256];
    const int tid = threadIdx.x;
    const int lane = tid & 63, wid = tid >> 6;
    const int d = blockIdx.x + blockIdx.y * 8;
    const int t = (d & 7) * 250 + (d >> 3);
    const int mt = t & 7, nt = t >> 3;
    const int m0 = mt * 256, n0 = nt * 128;
    const int wm = (wid >> 1) * 64, wn = (wid & 1) * 64;

    bf16x8 ar[4];
    auto loadA = [&](int k0) {
#pragma unroll
        for (int it = 0; it < 4; it++) {
            int q = it * 512 + tid;
            int row = q >> 3;
            int cs = q & 7;
            ar[it] = *(const bf16x8*)&Ab[(size_t)(m0 + row) * 512 + k0 + cs * 8];
        }
    };
    auto storeA = [&]() {
#pragma unroll
        for (int it = 0; it < 4; it++) {
            int q = it * 512 + tid;
            int row = q >> 3;
            int cs = q & 7;
            *(bf16x8*)&Asm[row * 64 + ((cs ^ (row & 7)) * 8)] = ar[it];
        }
    };

    if (PASS == 1) {
        for (int r = tid; r < 256; r += 512) lsh[r] = lse[m0 + r];
    }
    loadA(0);
    if (PASS == 1) __syncthreads();

    f32x4 acc[4][4];
#pragma unroll
    for (int i = 0; i < 4; i++)
#pragma unroll
        for (int j = 0; j < 4; j++) acc[i][j] = (f32x4){0.f, 0.f, 0.f, 0.f};

    for (int k0 = 0; k0 < 512; k0 += 64) {
        if (k0) __syncthreads();
        storeA();
#pragma unroll
        for (int it = 0; it < 2; it++) {
            int q = it * 512 + tid;
            int row = q >> 3;
            int cs = (q & 7) ^ (row & 7);
            GLL(Bt + (size_t)(n0 + row) * 512 + k0 + cs * 8, &Bsm[(it * 512 + wid * 64) * 8]);
        }
        __syncthreads();
        if (k0 + 64 < 512) loadA(k0 + 64);
#pragma unroll
        for (int kk = 0; kk < 2; kk++) {
            bf16x8 af[4], bfr[4];
#pragma unroll
            for (int i = 0; i < 4; i++) {
                int rowA = wm + i * 16 + (lane & 15);
                int ca = (kk * 4 + (lane >> 4)) ^ (rowA & 7);
                af[i] = *(const bf16x8*)&Asm[rowA * 64 + ca * 8];
                int rowB = wn + i * 16 + (lane & 15);
                int cb = (kk * 4 + (lane >> 4)) ^ (rowB & 7);
                bfr[i] = *(const bf16x8*)&Bsm[rowB * 64 + cb * 8];
            }
#pragma unroll
            for (int i = 0; i < 4; i++)
#pragma unroll
                for (int j = 0; j < 4; j++)
                    acc[i][j] = __builtin_amdgcn_mfma_f32_16x16x32_bf16(af[i], bfr[j], acc[i][j], 0, 0, 0);
        }
    }
    if (PASS == 0) {
#pragma unroll
        for (int i = 0; i < 4; i++) {
#pragma unroll
            for (int r = 0; r < 4; r++) {
                float mx = fmaxf(fmaxf(acc[i][0][r], acc[i][1][r]),
                                 fmaxf(acc[i][2][r], acc[i][3][r]));
                mx = fmaxf(mx, __shfl_xor(mx, 1));
                mx = fmaxf(mx, __shfl_xor(mx, 2));
                mx = fmaxf(mx, __shfl_xor(mx, 4));
                mx = fmaxf(mx, __shfl_xor(mx, 8));
                float s = __expf(acc[i][0][r] - mx) + __expf(acc[i][1][r] - mx) +
                          __expf(acc[i][2][r] - mx) + __expf(acc[i][3][r] - mx);
                s += __shfl_xor(s, 1); s += __shfl_xor(s, 2);
                s += __shfl_xor(s, 4); s += __shfl_xor(s, 8);
                if ((lane & 15) == 0) {
                    int li = i * 16 + (lane >> 4) * 4 + r;
                    pml[wid][li] = mx;
                    psl[wid][li] = s;
                }
            }
        }
        __syncthreads();
        if (tid < 256) {
            int g = tid >> 6, lr = tid & 63;
            int wa = g * 2, wb = g * 2 + 1;
            float m = fmaxf(pml[wa][lr], pml[wb][lr]);
            float s = psl[wa][lr] * __expf(pml[wa][lr] - m) + psl[wb][lr] * __expf(pml[wb][lr] - m);
            pm[(size_t)(m0 + g * 64 + lr) * 256 + nt] = m;
            psum[(size_t)(m0 + g * 64 + lr) * 256 + nt] = s;
        }
    } else {
#pragma unroll
        for (int i = 0; i < 4; i++)
#pragma unroll
            for (int j = 0; j < 4; j++)
#pragma unroll
                for (int r = 0; r < 4; r++) {
                    int rl = wm + i * 16 + (lane >> 4) * 4 + r;
                    int col = n0 + wn + j * 16 + (lane & 15);
                    Out[(size_t)(m0 + rl) * VOCAB + col] = acc[i][j][r] - lsh[rl];
                }
    }
}

// ---------------- lse reduce ----------------
__global__ __launch_bounds__(64) void lse_kernel(const float* __restrict__ pm,
                                                 const float* __restrict__ psum,
                                                 float* __restrict__ lse) {
    const int row = blockIdx.x, t = threadIdx.x;
    float m = -1e30f, s = 0.f;
    for (int nb = t; nb < 250; nb += 64) {
        float mm = pm[(size_t)row * 256 + nb];
        float ss = psum[(size_t)row * 256 + nb];
        float M = fmaxf(m, mm);
        s = s * __expf(m - M) + ss * __expf(mm - M);
        m = M;
    }
#pragma unroll
    for (int off = 32; off > 0; off >>= 1) {
        float mo = __shfl_xor(m, off), so = __shfl_xor(s, off);
        float M = fmaxf(m, mo);
        s = s * __expf(m - M) + so * __expf(mo - M);
        m = M;
    }
    if (t == 0) lse[row] = m + __logf(s);
}

// ---------------- orchestration ----------------
extern "C" void kernel_launch(void* const* d_in, const int* in_sizes, int n_in,
                              void* d_out, int out_size, void* d_ws, size_t ws_size,
                              hipStream_t stream) {
    const float* emb_src  = (const float*)d_in[0];
    const float* emb_tgt  = (const float*)d_in[1];
    const float* pos_emb  = (const float*)d_in[2];
    const float* time_emb = (const float*)d_in[3];
    const float* Wqkv_e   = (const float*)d_in[4];
    const float* Wo_e     = (const float*)d_in[5];
    const float* W1_e     = (const float*)d_in[6];
    const float* W2_e     = (const float*)d_in[7];
    const float* Wqkv_d   = (const float*)d_in[8];
    const float* Wo_d     = (const float*)d_in[9];
    const float* W1_d     = (const float*)d_in[10];
    const float* W2_d     = (const float*)d_in[11];
    const float* Wq_x     = (const float*)d_in[12];
    const float* Wkv_x    = (const float*)d_in[13];
    const float* Wo_x     = (const float*)d_in[14];
    const float* Wgen     = (const float*)d_in[15];
    const int* src_tokens = (const int*)d_in[16];
    const int* tgt_tokens = (const int*)d_in[17];
    const int* src_pos    = (const int*)d_in[18];
    const int* tgt_pos    = (const int*)d_in[19];

    char* w = (char*)d_ws;
    float* T_e0 = (float*)(w);
    float* T_e1 = (float*)(w + (4u << 20));
    float* T_d0 = (float*)(w + (8u << 20));
    float* T_d1 = (float*)(w + (12u << 20));
    float* T_d2 = (float*)(w + (16u << 20));
    unsigned short* kvx_bf = (unsigned short*)(w + (20u << 20));
    unsigned short* o_bf   = (unsigned short*)(w + (24u << 20));
    unsigned short* hid_bf = (unsigned short*)(w + (26u << 20));
    unsigned short* xd_bf  = (unsigned short*)(w + (34u << 20));
    float* pm   = (float*)(w + (36u << 20));
    float* psum = (float*)(w + (38u << 20));
    float* se0  = (float*)(w + (40u << 20));
    float* se1  = se0 + 32768;
    float* sd0  = se1 + 32768;
    float* sd1  = sd0 + 32768;
    float* sd2  = sd1 + 32768;
    float* lse  = sd2 + 32768;
    unsigned short* wts = (unsigned short*)(w + (41u << 20));

    unsigned short* WqkvE_t = wts;
    unsigned short* WoE_t   = WqkvE_t + 786432;
    unsigned short* W1E_t   = WoE_t   + 262144;
    unsigned short* W2E_t   = W1E_t   + 1048576;
    unsigned short* WqkvD_t = W2E_t   + 1048576;
    unsigned short* WoD_t   = WqkvD_t + 786432;
    unsigned short* W1D_t   = WoD_t   + 262144;
    unsigned short* W2D_t   = W1D_t   + 1048576;
    unsigned short* WqX_t   = W2D_t   + 1048576;
    unsigned short* WkvX_t  = WqX_t   + 262144;
    unsigned short* WoX_t   = WkvX_t  + 524288;
    unsigned short* Wgen_t  = WoX_t   + 262144;

    float* out = (float*)d_out;

    WTab tab;
    auto set = [&](int i, const float* s, unsigned short* d, int K, int N, int t0) {
        tab.d[i].src = s; tab.d[i].dst = d; tab.d[i].K = K; tab.d[i].N = N;
        tab.d[i].t0 = t0; tab.d[i].pad = 0;
    };
    set(0,  Wqkv_e, WqkvE_t, 512, 1536, 0);
    set(1,  Wo_e,   WoE_t,   512, 512,  768);
    set(2,  W1_e,   W1E_t,   512, 2048, 1024);
    set(3,  W2_e,   W2E_t,   2048, 512, 2048);
    set(4,  Wqkv_d, WqkvD_t, 512, 1536, 3072);
    set(5,  Wo_d,   WoD_t,   512, 512,  3840);
    set(6,  W1_d,   W1D_t,   512, 2048, 4096);
    set(7,  W2_d,   W2D_t,   2048, 512, 5120);
    set(8,  Wq_x,   WqX_t,   512, 512,  6144);
    set(9,  Wkv_x,  WkvX_t,  512, 1024, 6400);
    set(10, Wo_x,   WoX_t,   512, 512,  6912);
    set(11, Wgen,   Wgen_t,  512, 32000, 7168);
    wconv_all<<<23168, 256, 0, stream>>>(tab);

    const int n4 = NTOK * (DIM / 4);
    dim3 eb(256), eg((n4 + 255) / 256);
    embed_kernel<<<eg, eb, 0, stream>>>(emb_src, src_tokens, pos_emb, src_pos, T_e0, n4);
    embed_kernel<<<eg, eb, 0, stream>>>(emb_tgt, tgt_tokens, pos_emb, tgt_pos, T_d0, n4);

    const dim3 gFF(DFF / 64, NTOK / 128),
               gKV(1024 / 64, NTOK / 128),
               gBB(8, NTOK / 32);

    // -------- encoder --------
    {
        const float* scur = nullptr;
        for (int t = 0; t < DEPTH; t++) {
            const float* trow = time_emb + (size_t)t * DIM;
            fused_attn<0><<<256, 512, 0, stream>>>(T_e0, scur, pos_emb, trow, WqkvE_t, o_bf);
            gemm_bb<<<gBB, 256, 0, stream>>>(o_bf, WoE_t, T_e0, scur, T_e1, se0, NTOK, 512);
            gemm_rb<1><<<gFF, 256, 0, stream>>>(T_e1, se0, W1E_t, hid_bf, NTOK, DFF, 512);
            gemm_bb<<<gBB, 256, 0, stream>>>(hid_bf, W2E_t, T_e1, se0, T_e0, se1, NTOK, 2048);
            scur = se1;
        }
    }

    // cross-attn K/V from final encoder state (LN on the fly)
    gemm_rb<3><<<gKV, 256, 0, stream>>>(T_e0, se1, WkvX_t, kvx_bf, NTOK, 1024, 512);

    // -------- decoder --------
    {
        const float* scur = nullptr;
        for (int t = 0; t < DEPTH; t++) {
            const float* trow = time_emb + (size_t)t * DIM;
            fused_attn<1><<<256, 512, 0, stream>>>(T_d0, scur, pos_emb, trow, WqkvD_t, o_bf);
            gemm_bb<<<gBB, 256, 0, stream>>>(o_bf, WoD_t, T_d0, scur, T_d1, sd0, NTOK, 512);

            fused_xattn<<<256, 512, 0, stream>>>(T_d1, sd0, pos_emb, trow, WqX_t, kvx_bf, o_bf);
            gemm_bb<<<gBB, 256, 0, stream>>>(o_bf, WoX_t, T_d1, sd0, T_d2, sd1, NTOK, 512);

            gemm_rb<1><<<gFF, 256, 0, stream>>>(T_d2, sd1, W1D_t, hid_bf, NTOK, DFF, 512);
            gemm_bb<<<gBB, 256, 0, stream>>>(hid_bf, W2D_t, T_d2, sd1, T_d0, sd2, NTOK, 2048);
            scur = sd2;
        }
    }

    // -------- generator + log_softmax (two-pass, XCD-swizzled) --------
    ln_fin<<<NTOK, 64, 0, stream>>>(T_d0, sd2, xd_bf);
    gemm_gen<0><<<dim3(8, 250), 512, 0, stream>>>(xd_bf, Wgen_t, nullptr, pm, psum, nullptr);
    lse_kernel<<<NTOK, 64, 0, stream>>>(pm, psum, lse);
    gemm_gen<1><<<dim3(8, 250), 512, 0, stream>>>(xd_bf, Wgen_t, out, nullptr, nullptr, lse);
}

// Round 15
// 1677.715 us; speedup vs baseline: 1.7501x; 1.7501x over previous
//
#include <hip/hip_runtime.h>
#include <hip/hip_bf16.h>
#include <math.h>

#define H 8
#define DK 64
#define DIM 512
#define DFF 2048
#define DEPTH 8
#define VOCAB 32000
#define NTOK 2048

typedef float f32x4 __attribute__((ext_vector_type(4)));
typedef short bf16x8 __attribute__((ext_vector_type(8)));

static __device__ __forceinline__ unsigned short f2bf(float f) {
    unsigned u = __float_as_uint(f);
    return (unsigned short)((u + 0x7FFFu + ((u >> 16) & 1u)) >> 16);
}

#define GLL(src, dst) __builtin_amdgcn_global_load_lds( \
    (const __attribute__((address_space(1))) unsigned int*)(src), \
    (__attribute__((address_space(3))) unsigned int*)(dst), 16, 0, 0)

// load per-row LN stats (8 partial sum/sumsq pairs) -> mean + inv; identity if stats==null
static __device__ __forceinline__ void load_ln_stats(
    const float* __restrict__ stats, int base, int rows,
    float* Lm, float* Li, int tid, int nthr)
{
    for (int r = tid; r < rows; r += nthr) {
        float m = 0.f, inv = 1.f;
        if (stats) {
            const float* s = stats + (size_t)(base + r) * 16;
            float sum = 0.f, sq = 0.f;
#pragma unroll
            for (int b = 0; b < 8; b++) { sum += s[b * 2]; sq += s[b * 2 + 1]; }
            m = sum * (1.f / 512.f);
            float v = sq * (1.f / 512.f) - m * m;
            inv = 1.f / sqrtf(v + 1e-5f);
        }
        Lm[r] = m; Li[r] = inv;
    }
}

// ---------------- embed ----------------
__global__ void embed_kernel(const float* __restrict__ emb, const int* __restrict__ tok,
                             const float* __restrict__ pos, const int* __restrict__ pidx,
                             float* __restrict__ out, int n4) {
    int idx = blockIdx.x * blockDim.x + threadIdx.x;
    if (idx >= n4) return;
    int i = idx >> 7, d = idx & 127;
    float4 a = ((const float4*)emb)[(size_t)tok[i] * 128 + d];
    float4 b = ((const float4*)pos)[(size_t)pidx[i] * 128 + d];
    ((float4*)out)[idx] = make_float4(a.x + b.x, a.y + b.y, a.z + b.z, a.w + b.w);
}

// ---------------- batched weight convert+transpose ----------------
struct WD { const float* src; unsigned short* dst; int K; int N; int t0; int pad; };
struct WTab { WD d[12]; };

__global__ __launch_bounds__(256) void wconv_all(WTab tab) {
    __shared__ float t[32][33];
    const int bid = blockIdx.x;
    int w = 0;
#pragma unroll
    for (int i = 1; i < 12; i++) if (bid >= tab.d[i].t0) w = i;
    const float* W = tab.d[w].src;
    unsigned short* Wt = tab.d[w].dst;
    const int K = tab.d[w].K, N = tab.d[w].N;
    const int lt = bid - tab.d[w].t0;
    const int txc = N >> 5;
    const int n0 = (lt % txc) << 5, k0 = (lt / txc) << 5;
    const int tid = threadIdx.x;
    const int tx = tid & 31, ty = tid >> 5;
#pragma unroll
    for (int i = 0; i < 32; i += 8)
        t[ty + i][tx] = W[(size_t)(k0 + ty + i) * N + n0 + tx];
    __syncthreads();
#pragma unroll
    for (int i = 0; i < 32; i += 8)
        Wt[(size_t)(n0 + ty + i) * K + k0 + tx] = f2bf(t[tx][ty + i]);
}

// ---------------- gemm_rb: C = LN(T) @ Bt^T, double-buffered ----------------
// EPI 1: relu->bf16; 3: bf16.  BN = 64.
template<int EPI>
__global__ __launch_bounds__(256) void gemm_rb(
    const float* __restrict__ Tf,
    const float* __restrict__ stats,
    const unsigned short* __restrict__ Bt,
    unsigned short* __restrict__ Cb,
    int M, int N, int K)
{
    constexpr int BN = 64, JN = 2;
    __shared__ __align__(16) unsigned short Asm[2][128 * 64];
    __shared__ __align__(16) unsigned short Bsm[2][BN * 64];
    __shared__ float Lm[128], Li[128];
    const int tid = threadIdx.x;
    const int lane = tid & 63, wid = tid >> 6;
    const int m0 = blockIdx.y * 128, n0 = blockIdx.x * BN;
    const int wm = (wid >> 1) * 64, wn = (wid & 1) * (BN / 2);
    const int NK = K >> 6;

    float4 ar0[4], ar1[4];
    auto loadA = [&](int k0) {
#pragma unroll
        for (int it = 0; it < 4; it++) {
            int q = it * 256 + tid;
            int row = q >> 3;
            int cs = q & 7;
            const float* s = Tf + (size_t)(m0 + row) * K + k0 + cs * 8;
            ar0[it] = *(const float4*)s;
            ar1[it] = *(const float4*)(s + 4);
        }
    };
    auto storeA = [&](int buf) {
#pragma unroll
        for (int it = 0; it < 4; it++) {
            int q = it * 256 + tid;
            int row = q >> 3;
            int cs = q & 7;
            float m = Lm[row], iv = Li[row];
            unsigned short c8[8];
            c8[0] = f2bf((ar0[it].x - m) * iv); c8[1] = f2bf((ar0[it].y - m) * iv);
            c8[2] = f2bf((ar0[it].z - m) * iv); c8[3] = f2bf((ar0[it].w - m) * iv);
            c8[4] = f2bf((ar1[it].x - m) * iv); c8[5] = f2bf((ar1[it].y - m) * iv);
            c8[6] = f2bf((ar1[it].z - m) * iv); c8[7] = f2bf((ar1[it].w - m) * iv);
            *(bf16x8*)&Asm[buf][row * 64 + ((cs ^ (row & 7)) * 8)] = *(bf16x8*)c8;
        }
    };
    auto stageB = [&](int k0, int buf) {
#pragma unroll
        for (int it = 0; it < BN / 32; it++) {
            int q = it * 256 + tid;
            int row = q >> 3;
            int cs = (q & 7) ^ (row & 7);
            GLL(Bt + (size_t)(n0 + row) * K + k0 + cs * 8, &Bsm[buf][q * 8]);
        }
    };

    load_ln_stats(stats, m0, 128, Lm, Li, tid, 256);
    loadA(0);
    __syncthreads();
    storeA(0);
    stageB(0, 0);

    f32x4 acc[4][JN];
#pragma unroll
    for (int i = 0; i < 4; i++)
#pragma unroll
        for (int j = 0; j < JN; j++) acc[i][j] = (f32x4){0.f, 0.f, 0.f, 0.f};

    for (int kt = 0; kt < NK; kt++) {
        __syncthreads();
        const int cur = kt & 1, nxt = (kt + 1) & 1;
        if (kt + 1 < NK) {
            stageB((kt + 1) << 6, nxt);
            loadA((kt + 1) << 6);
        }
#pragma unroll
        for (int kk = 0; kk < 2; kk++) {
            bf16x8 af[4], bfr[JN];
#pragma unroll
            for (int i = 0; i < 4; i++) {
                int rowA = wm + i * 16 + (lane & 15);
                int ca = (kk * 4 + (lane >> 4)) ^ (rowA & 7);
                af[i] = *(const bf16x8*)&Asm[cur][rowA * 64 + ca * 8];
            }
#pragma unroll
            for (int j = 0; j < JN; j++) {
                int rowB = wn + j * 16 + (lane & 15);
                int cb = (kk * 4 + (lane >> 4)) ^ (rowB & 7);
                bfr[j] = *(const bf16x8*)&Bsm[cur][rowB * 64 + cb * 8];
            }
#pragma unroll
            for (int i = 0; i < 4; i++)
#pragma unroll
                for (int j = 0; j < JN; j++)
                    acc[i][j] = __builtin_amdgcn_mfma_f32_16x16x32_bf16(af[i], bfr[j], acc[i][j], 0, 0, 0);
        }
        if (kt + 1 < NK) storeA(nxt);
    }
#pragma unroll
    for (int i = 0; i < 4; i++)
#pragma unroll
        for (int j = 0; j < JN; j++)
#pragma unroll
            for (int r = 0; r < 4; r++) {
                int row = m0 + wm + i * 16 + (lane >> 4) * 4 + r;
                int col = n0 + wn + j * 16 + (lane & 15);
                size_t idx = (size_t)row * N + col;
                float v = acc[i][j][r];
                if (EPI == 1) Cb[idx] = f2bf(fmaxf(v, 0.f));
                if (EPI == 3) Cb[idx] = f2bf(v);
            }
}

// ---------------- gemm_bb: Tout = LN(Tin) + A @ Bt^T, double-buffered ----------------
__global__ __launch_bounds__(256) void gemm_bb(
    const unsigned short* __restrict__ A,
    const unsigned short* __restrict__ Bt,
    const float* __restrict__ Tin,
    const float* __restrict__ statsIn,
    float* __restrict__ Tout,
    float* __restrict__ statsOut,
    int M, int K)
{
    __shared__ __align__(16) unsigned short Asm[2][32 * 64];
    __shared__ __align__(16) unsigned short Bsm[2][64 * 64];
    __shared__ float Lm[32], Li[32];
    __shared__ float sredS[4][32], sredQ[4][32];
    const int tid = threadIdx.x;
    const int lane = tid & 63, wid = tid >> 6;
    const int nb = blockIdx.x;
    const int m0 = blockIdx.y * 32, n0 = nb * 64;
    const int wn = wid * 16;
    const int NK = K >> 6;

    auto stage = [&](int k0, int buf) {
        {
            int q = tid;
            int row = q >> 3;
            int cs = (q & 7) ^ (row & 7);
            GLL(A + (size_t)(m0 + row) * K + k0 + cs * 8, &Asm[buf][q * 8]);
        }
#pragma unroll
        for (int it = 0; it < 2; it++) {
            int q = it * 256 + tid;
            int row = q >> 3;
            int cs = (q & 7) ^ (row & 7);
            GLL(Bt + (size_t)(n0 + row) * K + k0 + cs * 8, &Bsm[buf][q * 8]);
        }
    };

    load_ln_stats(statsIn, m0, 32, Lm, Li, tid, 256);
    stage(0, 0);

    f32x4 acc[2];
#pragma unroll
    for (int i = 0; i < 2; i++) acc[i] = (f32x4){0.f, 0.f, 0.f, 0.f};

    for (int kt = 0; kt < NK; kt++) {
        __syncthreads();
        const int cur = kt & 1, nxt = (kt + 1) & 1;
        if (kt + 1 < NK) stage((kt + 1) << 6, nxt);
#pragma unroll
        for (int kd = 0; kd < 2; kd++) {
            int rowB = wn + (lane & 15);
            int cb = (kd * 4 + (lane >> 4)) ^ (rowB & 7);
            bf16x8 bfr = *(const bf16x8*)&Bsm[cur][rowB * 64 + cb * 8];
#pragma unroll
            for (int i = 0; i < 2; i++) {
                int rowA = i * 16 + (lane & 15);
                int ca = (kd * 4 + (lane >> 4)) ^ (rowA & 7);
                bf16x8 af = *(const bf16x8*)&Asm[cur][rowA * 64 + ca * 8];
                acc[i] = __builtin_amdgcn_mfma_f32_16x16x32_bf16(af, bfr, acc[i], 0, 0, 0);
            }
        }
    }
#pragma unroll
    for (int i = 0; i < 2; i++) {
#pragma unroll
        for (int r = 0; r < 4; r++) {
            int rl = i * 16 + (lane >> 4) * 4 + r;
            int row = m0 + rl;
            int col = n0 + wn + (lane & 15);
            size_t idx = (size_t)row * DIM + col;
            float rv = (Tin[idx] - Lm[rl]) * Li[rl];
            float v = acc[i][r] + rv;
            Tout[idx] = v;
            float s = v, q = v * v;
            s += __shfl_xor(s, 1); s += __shfl_xor(s, 2);
            s += __shfl_xor(s, 4); s += __shfl_xor(s, 8);
            q += __shfl_xor(q, 1); q += __shfl_xor(q, 2);
            q += __shfl_xor(q, 4); q += __shfl_xor(q, 8);
            if ((lane & 15) == 0) { sredS[wid][rl] = s; sredQ[wid][rl] = q; }
        }
    }
    __syncthreads();
    if (tid < 32) {
        int row = tid;
        float s = sredS[0][row] + sredS[1][row] + sredS[2][row] + sredS[3][row];
        float q = sredQ[0][row] + sredQ[1][row] + sredQ[2][row] + sredQ[3][row];
        statsOut[(size_t)(m0 + row) * 16 + nb * 2] = s;
        statsOut[(size_t)(m0 + row) * 16 + nb * 2 + 1] = q;
    }
}

// ---------------- attention phase 2: split keys across wave pairs ----------------
template<int CAUSAL>
static __device__ __forceinline__ void attn_phase2_split(
    const unsigned short* Qs, const unsigned short* Ks, const unsigned short* Vt,
    unsigned short* Psw, float* dumpf,
    int qh, int wid, int lane, int tok0, int h,
    unsigned short* __restrict__ O)
{
    const int qg = wid & 3, kh = wid >> 2;
    bf16x8 qa[2];
#pragma unroll
    for (int kd = 0; kd < 2; kd++) {
        int qr = qg * 16 + (lane & 15);
        int ch = (kd * 4 + (lane >> 4)) ^ (qr & 7);
        qa[kd] = *(const bf16x8*)&Qs[qr * 64 + ch * 8];
    }
    int jn, kcn;
    if (!CAUSAL)      { jn = 4; kcn = 2; }
    else if (kh > qh) { jn = 0; kcn = 0; }
    else if (kh < qh) { jn = 4; kcn = 2; }
    else              { kcn = (qg >> 1) + 1; jn = kcn * 2; }

    float zr[4] = {0.f, 0.f, 0.f, 0.f};
    f32x4 oacc[4];
#pragma unroll
    for (int dt = 0; dt < 4; dt++) oacc[dt] = (f32x4){0.f, 0.f, 0.f, 0.f};

    if (jn > 0) {
        f32x4 sacc[4];
#pragma unroll
        for (int j = 0; j < 4; j++) sacc[j] = (f32x4){0.f, 0.f, 0.f, 0.f};
#pragma unroll 2
        for (int kd = 0; kd < 2; kd++) {
            for (int jj = 0; jj < jn; jj++) {
                int kr = kh * 64 + jj * 16 + (lane & 15);
                int ch = (kd * 4 + (lane >> 4)) ^ (kr & 7);
                bf16x8 kf = *(const bf16x8*)&Ks[kr * 64 + ch * 8];
                sacc[jj] = __builtin_amdgcn_mfma_f32_16x16x32_bf16(qa[kd], kf, sacc[jj], 0, 0, 0);
            }
        }
        int qbase = qh * 64 + qg * 16 + (lane >> 4) * 4;
        for (int jj = 0; jj < jn; jj++) {
            int kcol = kh * 64 + jj * 16 + (lane & 15);
#pragma unroll
            for (int rr = 0; rr < 4; rr++) {
                float p = __expf(sacc[jj][rr] * 0.125f);
                if (CAUSAL && kcol > qbase + rr) p = 0.f;
                zr[rr] += p;
                int prow = (lane >> 4) * 4 + rr;
                int ch = ((jj * 2 + ((lane & 15) >> 3)) ^ (prow & 7));
                Psw[prow * 64 + ch * 8 + (lane & 7)] = f2bf(p);
            }
        }
        for (int kcl = 0; kcl < kcn; kcl++) {
            bf16x8 pa;
            {
                int prow = lane & 15;
                int ch = (kcl * 4 + (lane >> 4)) ^ (prow & 7);
                pa = *(const bf16x8*)&Psw[prow * 64 + ch * 8];
            }
            int kcg = kh * 2 + kcl;
#pragma unroll
            for (int dt = 0; dt < 4; dt++) {
                int d = dt * 16 + (lane & 15);
                bf16x8 vf = *(const bf16x8*)&Vt[d * 132 + (kcg * 4 + (lane >> 4)) * 8];
                oacc[dt] = __builtin_amdgcn_mfma_f32_16x16x32_bf16(pa, vf, oacc[dt], 0, 0, 0);
            }
        }
    }
    __syncthreads();
    if (kh == 1) {
        float* dst = dumpf + (size_t)(qg * 64 + lane) * 20;
#pragma unroll
        for (int dt = 0; dt < 4; dt++)
#pragma unroll
            for (int rr = 0; rr < 4; rr++) dst[dt * 4 + rr] = oacc[dt][rr];
#pragma unroll
        for (int rr = 0; rr < 4; rr++) dst[16 + rr] = zr[rr];
    }
    __syncthreads();
    if (kh == 0) {
        const float* src = dumpf + (size_t)(qg * 64 + lane) * 20;
#pragma unroll
        for (int dt = 0; dt < 4; dt++)
#pragma unroll
            for (int rr = 0; rr < 4; rr++) oacc[dt][rr] += src[dt * 4 + rr];
#pragma unroll
        for (int rr = 0; rr < 4; rr++) {
            float z = zr[rr] + src[16 + rr];
            z += __shfl_xor(z, 1); z += __shfl_xor(z, 2);
            z += __shfl_xor(z, 4); z += __shfl_xor(z, 8);
            zr[rr] = 1.f / (z + 1e-9f);
        }
#pragma unroll
        for (int dt = 0; dt < 4; dt++)
#pragma unroll
            for (int rr = 0; rr < 4; rr++) {
                int qrow = tok0 + qh * 64 + qg * 16 + (lane >> 4) * 4 + rr;
                O[(size_t)qrow * DIM + h * 64 + dt * 16 + (lane & 15)] =
                    f2bf(oacc[dt][rr] * zr[rr]);
            }
    }
}

// ---------------- fused QKV-GEMM + self-attention: 256 blocks (b,h,qhalf) ----------------
// Q cols computed only by own-half waves (static, fully-unrolled branches).
template<int CAUSAL>
__global__ __launch_bounds__(512) void fused_attn(
    const float* __restrict__ Tf,
    const float* __restrict__ stats,
    const float* __restrict__ pos,
    const float* __restrict__ trow,
    const unsigned short* __restrict__ WqkvT,
    unsigned short* __restrict__ O)
{
    __shared__ __align__(16) unsigned short smem[28928];
    __shared__ float LmA[128], LiA[128];
    unsigned short* Asm = smem;
    unsigned short* Bsm = smem + 8192;
    unsigned short* Qs  = smem;
    unsigned short* Ks  = smem + 4096;
    unsigned short* Vt  = smem + 12288;
    float* dumpf = (float*)smem;
    const int tid = threadIdx.x;
    const int lane = tid & 63, wid = tid >> 6;
    unsigned short* Psw = smem + 20736 + wid * 1024;
    const int blk = blockIdx.x;
    const int qh = blk & 1, h = (blk >> 1) & 7, b = blk >> 4;
    const int tok0 = b * 128;
    const int wr = wid * 16;
    const bool own = (wid >> 2) == qh;   // wave-uniform: this wave's rows are in our q-half

    load_ln_stats(stats, tok0, 128, LmA, LiA, tid, 512);
    __syncthreads();

    f32x4 acc[12];
#pragma unroll
    for (int c = 0; c < 12; c++) acc[c] = (f32x4){0.f, 0.f, 0.f, 0.f};

    for (int k0 = 0; k0 < 512; k0 += 64) {
        if (k0) __syncthreads();
#pragma unroll
        for (int it = 0; it < 3; it++) {
            int q = it * 512 + wid * 64 + lane;
            int r = q >> 3;
            int cs = (q & 7) ^ (r & 7);
            int srow = (r < 64) ? (h * 64 + r)
                     : (r < 128) ? (512 + h * 64 + (r - 64))
                                 : (1024 + h * 64 + (r - 128));
            GLL(WqkvT + (size_t)srow * 512 + k0 + cs * 8, &Bsm[(it * 512 + wid * 64) * 8]);
        }
#pragma unroll
        for (int it = 0; it < 2; it++) {
            int q = it * 512 + tid;
            int row = q >> 3;
            int cs = q & 7;
            const float* s = Tf + (size_t)(tok0 + row) * 512 + k0 + cs * 8;
            const float* pp = pos + (size_t)row * 512 + k0 + cs * 8;
            const float* tt = trow + k0 + cs * 8;
            float4 u0 = *(const float4*)s, u1 = *(const float4*)(s + 4);
            float4 p0 = *(const float4*)pp, p1 = *(const float4*)(pp + 4);
            float4 t0 = *(const float4*)tt, t1 = *(const float4*)(tt + 4);
            float m = LmA[row], iv = LiA[row];
            unsigned short c8[8];
            c8[0] = f2bf((u0.x - m) * iv + p0.x + t0.x);
            c8[1] = f2bf((u0.y - m) * iv + p0.y + t0.y);
            c8[2] = f2bf((u0.z - m) * iv + p0.z + t0.z);
            c8[3] = f2bf((u0.w - m) * iv + p0.w + t0.w);
            c8[4] = f2bf((u1.x - m) * iv + p1.x + t1.x);
            c8[5] = f2bf((u1.y - m) * iv + p1.y + t1.y);
            c8[6] = f2bf((u1.z - m) * iv + p1.z + t1.z);
            c8[7] = f2bf((u1.w - m) * iv + p1.w + t1.w);
            *(bf16x8*)&Asm[row * 64 + ((cs ^ (row & 7)) * 8)] = *(bf16x8*)c8;
        }
        __syncthreads();
#pragma unroll
        for (int kk = 0; kk < 2; kk++) {
            int rowA = wr + (lane & 15);
            int ca = (kk * 4 + (lane >> 4)) ^ (rowA & 7);
            bf16x8 af = *(const bf16x8*)&Asm[rowA * 64 + ca * 8];
            if (own) {
#pragma unroll
                for (int c = 0; c < 12; c++) {
                    int rowB = c * 16 + (lane & 15);
                    int cb = (kk * 4 + (lane >> 4)) ^ (rowB & 7);
                    bf16x8 bfr = *(const bf16x8*)&Bsm[rowB * 64 + cb * 8];
                    acc[c] = __builtin_amdgcn_mfma_f32_16x16x32_bf16(af, bfr, acc[c], 0, 0, 0);
                }
            } else {
#pragma unroll
                for (int c = 4; c < 12; c++) {
                    int rowB = c * 16 + (lane & 15);
                    int cb = (kk * 4 + (lane >> 4)) ^ (rowB & 7);
                    bf16x8 bfr = *(const bf16x8*)&Bsm[rowB * 64 + cb * 8];
                    acc[c] = __builtin_amdgcn_mfma_f32_16x16x32_bf16(af, bfr, acc[c], 0, 0, 0);
                }
            }
        }
    }
    __syncthreads();
#pragma unroll
    for (int c = 0; c < 12; c++)
#pragma unroll
        for (int r = 0; r < 4; r++) {
            int token = wr + (lane >> 4) * 4 + r;
            int col = (c & 3) * 16 + (lane & 15);
            unsigned short v = f2bf(acc[c][r]);
            if (c < 4) {
                int tl = token - qh * 64;
                if (tl >= 0 && tl < 64)
                    Qs[tl * 64 + (((col >> 3) ^ (tl & 7)) * 8) + (col & 7)] = v;
            } else if (c < 8) {
                Ks[token * 64 + (((col >> 3) ^ (token & 7)) * 8) + (col & 7)] = v;
            } else {
                Vt[col * 132 + token] = v;
            }
        }
    __syncthreads();
    attn_phase2_split<CAUSAL>(Qs, Ks, Vt, Psw, dumpf, qh, wid, lane, tok0, h, O);
}

// ---------------- fused Q-GEMM + cross-attention: 256 blocks (b,h,qhalf) ----------------
__global__ __launch_bounds__(512) void fused_xattn(
    const float* __restrict__ Tf,
    const float* __restrict__ stats,
    const float* __restrict__ pos,
    const float* __restrict__ trow,
    const unsigned short* __restrict__ WqT,
    const unsigned short* __restrict__ kvx,
    unsigned short* __restrict__ O)
{
    __shared__ __align__(16) unsigned short smem[28928];
    __shared__ float LmA[64], LiA[64];
    unsigned short* Qs  = smem;
    unsigned short* Ks  = smem + 4096;
    unsigned short* Vt  = smem + 12288;
    unsigned short* Asm = smem + 20736;
    unsigned short* Bsm = smem + 24832;
    float* dumpf = (float*)smem;
    const int tid = threadIdx.x;
    const int lane = tid & 63, wid = tid >> 6;
    unsigned short* Psw = smem + 20736 + wid * 1024;
    const int blk = blockIdx.x;
    const int qh = blk & 1, h = (blk >> 1) & 7, b = blk >> 4;
    const int tok0 = b * 128;

    load_ln_stats(stats, tok0 + qh * 64, 64, LmA, LiA, tid, 512);

    if (wid >= 4) {
        int st = tid - 256;
        int r = st >> 1, c0 = (st & 1) * 4;
        const unsigned short* Kg = kvx + (size_t)(tok0 + r) * 1024 + h * 64;
        const unsigned short* Vg = Kg + 512;
#pragma unroll
        for (int c = c0; c < c0 + 4; c++) {
            bf16x8 kv = *(const bf16x8*)&Kg[c * 8];
            *(bf16x8*)&Ks[r * 64 + ((c ^ (r & 7)) * 8)] = kv;
            bf16x8 vv = *(const bf16x8*)&Vg[c * 8];
#pragma unroll
            for (int j = 0; j < 8; j++)
                Vt[(c * 8 + j) * 132 + r] = (unsigned short)vv[j];
        }
    }
    __syncthreads();

    f32x4 acc[4];
#pragma unroll
    for (int c = 0; c < 4; c++) acc[c] = (f32x4){0.f, 0.f, 0.f, 0.f};

    for (int k0 = 0; k0 < 512; k0 += 64) {
        if (k0) __syncthreads();
        if (tid < 256) {
#pragma unroll
            for (int it = 0; it < 2; it++) {
                int q = it * 256 + tid;
                int r = q >> 3;
                int cs = (q & 7) ^ (r & 7);
                GLL(WqT + (size_t)(h * 64 + r) * 512 + k0 + cs * 8, &Bsm[q * 8]);
            }
#pragma unroll
            for (int it = 0; it < 2; it++) {
                int q = it * 256 + tid;
                int row = q >> 3;
                int cs = q & 7;
                const float* s = Tf + (size_t)(tok0 + qh * 64 + row) * 512 + k0 + cs * 8;
                const float* pp = pos + (size_t)(qh * 64 + row) * 512 + k0 + cs * 8;
                const float* tt = trow + k0 + cs * 8;
                float4 u0 = *(const float4*)s, u1 = *(const float4*)(s + 4);
                float4 p0 = *(const float4*)pp, p1 = *(const float4*)(pp + 4);
                float4 t0 = *(const float4*)tt, t1 = *(const float4*)(tt + 4);
                float m = LmA[row], iv = LiA[row];
                unsigned short c8[8];
                c8[0] = f2bf((u0.x - m) * iv + p0.x + t0.x);
                c8[1] = f2bf((u0.y - m) * iv + p0.y + t0.y);
                c8[2] = f2bf((u0.z - m) * iv + p0.z + t0.z);
                c8[3] = f2bf((u0.w - m) * iv + p0.w + t0.w);
                c8[4] = f2bf((u1.x - m) * iv + p1.x + t1.x);
                c8[5] = f2bf((u1.y - m) * iv + p1.y + t1.y);
                c8[6] = f2bf((u1.z - m) * iv + p1.z + t1.z);
                c8[7] = f2bf((u1.w - m) * iv + p1.w + t1.w);
                *(bf16x8*)&Asm[row * 64 + ((cs ^ (row & 7)) * 8)] = *(bf16x8*)c8;
            }
        }
        __syncthreads();
        if (wid < 4) {
#pragma unroll
            for (int kk = 0; kk < 2; kk++) {
                int rowA = wid * 16 + (lane & 15);
                int ca = (kk * 4 + (lane >> 4)) ^ (rowA & 7);
                bf16x8 af = *(const bf16x8*)&Asm[rowA * 64 + ca * 8];
#pragma unroll
                for (int c = 0; c < 4; c++) {
                    int rowB = c * 16 + (lane & 15);
                    int cb = (kk * 4 + (lane >> 4)) ^ (rowB & 7);
                    bf16x8 bfr = *(const bf16x8*)&Bsm[rowB * 64 + cb * 8];
                    acc[c] = __builtin_amdgcn_mfma_f32_16x16x32_bf16(af, bfr, acc[c], 0, 0, 0);
                }
            }
        }
    }
    __syncthreads();
    if (wid < 4) {
#pragma unroll
        for (int c = 0; c < 4; c++)
#pragma unroll
            for (int r = 0; r < 4; r++) {
                int tl = wid * 16 + (lane >> 4) * 4 + r;
                int col = c * 16 + (lane & 15);
                Qs[tl * 64 + (((col >> 3) ^ (tl & 7)) * 8) + (col & 7)] = f2bf(acc[c][r]);
            }
    }
    __syncthreads();
    attn_phase2_split<0>(Qs, Ks, Vt, Psw, dumpf, qh, wid, lane, tok0, h, O);
}

// ---------------- ln finalize: xb = bf16(LN(T)) using stats ----------------
__global__ __launch_bounds__(64) void ln_fin(const float* __restrict__ T,
                                             const float* __restrict__ stats,
                                             unsigned short* __restrict__ outb) {
    const int row = blockIdx.x, lane = threadIdx.x;
    const float* st = stats + (size_t)row * 16;
    float sum = 0.f, sq = 0.f;
#pragma unroll
    for (int b = 0; b < 8; b++) { sum += st[b * 2]; sq += st[b * 2 + 1]; }
    float m = sum * (1.f / 512.f);
    float v = sq * (1.f / 512.f) - m * m;
    float inv = 1.f / sqrtf(v + 1e-5f);
    const float* p = T + (size_t)row * DIM;
    unsigned short* qb = outb + (size_t)row * DIM;
#pragma unroll
    for (int i = 0; i < 8; i++)
        qb[lane + i * 64] = f2bf((p[lane + i * 64] - m) * inv);
}

// ---------------- generator: 256x128 tile, XCD-swizzled, two-pass ----------------
template<int PASS>
__global__ __launch_bounds__(512) void gemm_gen(
    const unsigned short* __restrict__ Ab,
    const unsigned short* __restrict__ Bt,
    float* __restrict__ Out,
    float* __restrict__ pm,
    float* __restrict__ psum,
    const float* __restrict__ lse)
{
    __shared__ __align__(16) unsigned short Asm[256 * 64];
    __shared__ __align__(16) unsigned short Bsm[128 * 64];
    __shared__ float pml[8][64];
    __shared__ float psl[8][64];
    __shared__ float lsh[256];
    const int tid = threadIdx.x;
    const int lane = tid & 63, wid = tid >> 6;
    const int d = blockIdx.x + blockIdx.y * 8;
    const int t = (d & 7) * 250 + (d >> 3);
    const int mt = t & 7, nt = t >> 3;
    const int m0 = mt * 256, n0 = nt * 128;
    const int wm = (wid >> 1) * 64, wn = (wid & 1) * 64;

    if (PASS == 1) {
        for (int r = tid; r < 256; r += 512) lsh[r] = lse[m0 + r];
        __syncthreads();
    }

    f32x4 acc[4][4];
#pragma unroll
    for (int i = 0; i < 4; i++)
#pragma unroll
        for (int j = 0; j < 4; j++) acc[i][j] = (f32x4){0.f, 0.f, 0.f, 0.f};

    for (int k0 = 0; k0 < 512; k0 += 64) {
        if (k0 || PASS == 1) __syncthreads();
#pragma unroll
        for (int it = 0; it < 2; it++) {
            int q = it * 512 + tid;
            int row = q >> 3;
            int cs = (q & 7) ^ (row & 7);
            GLL(Bt + (size_t)(n0 + row) * 512 + k0 + cs * 8, &Bsm[(it * 512 + wid * 64) * 8]);
        }
#pragma unroll
        for (int it = 0; it < 4; it++) {
            int q = it * 512 + tid;
            int row = q >> 3;
            int cs = (q & 7) ^ (row & 7);
            GLL(Ab + (size_t)(m0 + row) * 512 + k0 + cs * 8, &Asm[(it * 512 + wid * 64) * 8]);
        }
        __syncthreads();
#pragma unroll
        for (int kk = 0; kk < 2; kk++) {
            bf16x8 af[4], bfr[4];
#pragma unroll
            for (int i = 0; i < 4; i++) {
                int rowA = wm + i * 16 + (lane & 15);
                int ca = (kk * 4 + (lane >> 4)) ^ (rowA & 7);
                af[i] = *(const bf16x8*)&Asm[rowA * 64 + ca * 8];
                int rowB = wn + i * 16 + (lane & 15);
                int cb = (kk * 4 + (lane >> 4)) ^ (rowB & 7);
                bfr[i] = *(const bf16x8*)&Bsm[rowB * 64 + cb * 8];
            }
#pragma unroll
            for (int i = 0; i < 4; i++)
#pragma unroll
                for (int j = 0; j < 4; j++)
                    acc[i][j] = __builtin_amdgcn_mfma_f32_16x16x32_bf16(af[i], bfr[j], acc[i][j], 0, 0, 0);
        }
    }
    if (PASS == 0) {
#pragma unroll
        for (int i = 0; i < 4; i++) {
#pragma unroll
            for (int r = 0; r < 4; r++) {
                float mx = fmaxf(fmaxf(acc[i][0][r], acc[i][1][r]),
                                 fmaxf(acc[i][2][r], acc[i][3][r]));
                mx = fmaxf(mx, __shfl_xor(mx, 1));
                mx = fmaxf(mx, __shfl_xor(mx, 2));
                mx = fmaxf(mx, __shfl_xor(mx, 4));
                mx = fmaxf(mx, __shfl_xor(mx, 8));
                float s = __expf(acc[i][0][r] - mx) + __expf(acc[i][1][r] - mx) +
                          __expf(acc[i][2][r] - mx) + __expf(acc[i][3][r] - mx);
                s += __shfl_xor(s, 1); s += __shfl_xor(s, 2);
                s += __shfl_xor(s, 4); s += __shfl_xor(s, 8);
                if ((lane & 15) == 0) {
                    int li = i * 16 + (lane >> 4) * 4 + r;
                    pml[wid][li] = mx;
                    psl[wid][li] = s;
                }
            }
        }
        __syncthreads();
        if (tid < 256) {
            int g = tid >> 6, lr = tid & 63;
            int wa = g * 2, wb = g * 2 + 1;
            float m = fmaxf(pml[wa][lr], pml[wb][lr]);
            float s = psl[wa][lr] * __expf(pml[wa][lr] - m) + psl[wb][lr] * __expf(pml[wb][lr] - m);
            pm[(size_t)(m0 + g * 64 + lr) * 256 + nt] = m;
            psum[(size_t)(m0 + g * 64 + lr) * 256 + nt] = s;
        }
    } else {
#pragma unroll
        for (int i = 0; i < 4; i++)
#pragma unroll
            for (int j = 0; j < 4; j++)
#pragma unroll
                for (int r = 0; r < 4; r++) {
                    int rl = wm + i * 16 + (lane >> 4) * 4 + r;
                    int col = n0 + wn + j * 16 + (lane & 15);
                    Out[(size_t)(m0 + rl) * VOCAB + col] = acc[i][j][r] - lsh[rl];
                }
    }
}

// ---------------- lse reduce ----------------
__global__ __launch_bounds__(64) void lse_kernel(const float* __restrict__ pm,
                                                 const float* __restrict__ psum,
                                                 float* __restrict__ lse) {
    const int row = blockIdx.x, t = threadIdx.x;
    float m = -1e30f, s = 0.f;
    for (int nb = t; nb < 250; nb += 64) {
        float mm = pm[(size_t)row * 256 + nb];
        float ss = psum[(size_t)row * 256 + nb];
        float M = fmaxf(m, mm);
        s = s * __expf(m - M) + ss * __expf(mm - M);
        m = M;
    }
#pragma unroll
    for (int off = 32; off > 0; off >>= 1) {
        float mo = __shfl_xor(m, off), so = __shfl_xor(s, off);
        float M = fmaxf(m, mo);
        s = s * __expf(m - M) + so * __expf(mo - M);
        m = M;
    }
    if (t == 0) lse[row] = m + __logf(s);
}

// ---------------- orchestration ----------------
extern "C" void kernel_launch(void* const* d_in, const int* in_sizes, int n_in,
                              void* d_out, int out_size, void* d_ws, size_t ws_size,
                              hipStream_t stream) {
    const float* emb_src  = (const float*)d_in[0];
    const float* emb_tgt  = (const float*)d_in[1];
    const float* pos_emb  = (const float*)d_in[2];
    const float* time_emb = (const float*)d_in[3];
    const float* Wqkv_e   = (const float*)d_in[4];
    const float* Wo_e     = (const float*)d_in[5];
    const float* W1_e     = (const float*)d_in[6];
    const float* W2_e     = (const float*)d_in[7];
    const float* Wqkv_d   = (const float*)d_in[8];
    const float* Wo_d     = (const float*)d_in[9];
    const float* W1_d     = (const float*)d_in[10];
    const float* W2_d     = (const float*)d_in[11];
    const float* Wq_x     = (const float*)d_in[12];
    const float* Wkv_x    = (const float*)d_in[13];
    const float* Wo_x     = (const float*)d_in[14];
    const float* Wgen     = (const float*)d_in[15];
    const int* src_tokens = (const int*)d_in[16];
    const int* tgt_tokens = (const int*)d_in[17];
    const int* src_pos    = (const int*)d_in[18];
    const int* tgt_pos    = (const int*)d_in[19];

    char* w = (char*)d_ws;
    float* T_e0 = (float*)(w);
    float* T_e1 = (float*)(w + (4u << 20));
    float* T_d0 = (float*)(w + (8u << 20));
    float* T_d1 = (float*)(w + (12u << 20));
    float* T_d2 = (float*)(w + (16u << 20));
    unsigned short* kvx_bf = (unsigned short*)(w + (20u << 20));
    unsigned short* o_bf   = (unsigned short*)(w + (24u << 20));
    unsigned short* hid_bf = (unsigned short*)(w + (26u << 20));
    unsigned short* xd_bf  = (unsigned short*)(w + (34u << 20));
    float* pm   = (float*)(w + (36u << 20));
    float* psum = (float*)(w + (38u << 20));
    float* se0  = (float*)(w + (40u << 20));
    float* se1  = se0 + 32768;
    float* sd0  = se1 + 32768;
    float* sd1  = sd0 + 32768;
    float* sd2  = sd1 + 32768;
    float* lse  = sd2 + 32768;
    unsigned short* wts = (unsigned short*)(w + (41u << 20));

    unsigned short* WqkvE_t = wts;
    unsigned short* WoE_t   = WqkvE_t + 786432;
    unsigned short* W1E_t   = WoE_t   + 262144;
    unsigned short* W2E_t   = W1E_t   + 1048576;
    unsigned short* WqkvD_t = W2E_t   + 1048576;
    unsigned short* WoD_t   = WqkvD_t + 786432;
    unsigned short* W1D_t   = WoD_t   + 262144;
    unsigned short* W2D_t   = W1D_t   + 1048576;
    unsigned short* WqX_t   = W2D_t   + 1048576;
    unsigned short* WkvX_t  = WqX_t   + 262144;
    unsigned short* WoX_t   = WkvX_t  + 524288;
    unsigned short* Wgen_t  = WoX_t   + 262144;

    float* out = (float*)d_out;

    WTab tab;
    auto set = [&](int i, const float* s, unsigned short* d, int K, int N, int t0) {
        tab.d[i].src = s; tab.d[i].dst = d; tab.d[i].K = K; tab.d[i].N = N;
        tab.d[i].t0 = t0; tab.d[i].pad = 0;
    };
    set(0,  Wqkv_e, WqkvE_t, 512, 1536, 0);
    set(1,  Wo_e,   WoE_t,   512, 512,  768);
    set(2,  W1_e,   W1E_t,   512, 2048, 1024);
    set(3,  W2_e,   W2E_t,   2048, 512, 2048);
    set(4,  Wqkv_d, WqkvD_t, 512, 1536, 3072);
    set(5,  Wo_d,   WoD_t,   512, 512,  3840);
    set(6,  W1_d,   W1D_t,   512, 2048, 4096);
    set(7,  W2_d,   W2D_t,   2048, 512, 5120);
    set(8,  Wq_x,   WqX_t,   512, 512,  6144);
    set(9,  Wkv_x,  WkvX_t,  512, 1024, 6400);
    set(10, Wo_x,   WoX_t,   512, 512,  6912);
    set(11, Wgen,   Wgen_t,  512, 32000, 7168);
    wconv_all<<<23168, 256, 0, stream>>>(tab);

    const int n4 = NTOK * (DIM / 4);
    dim3 eb(256), eg((n4 + 255) / 256);
    embed_kernel<<<eg, eb, 0, stream>>>(emb_src, src_tokens, pos_emb, src_pos, T_e0, n4);
    embed_kernel<<<eg, eb, 0, stream>>>(emb_tgt, tgt_tokens, pos_emb, tgt_pos, T_d0, n4);

    const dim3 gFF(DFF / 64, NTOK / 128),
               gKV(1024 / 64, NTOK / 128),
               gBB(8, NTOK / 32);

    // -------- encoder --------
    {
        const float* scur = nullptr;
        for (int t = 0; t < DEPTH; t++) {
            const float* trow = time_emb + (size_t)t * DIM;
            fused_attn<0><<<256, 512, 0, stream>>>(T_e0, scur, pos_emb, trow, WqkvE_t, o_bf);
            gemm_bb<<<gBB, 256, 0, stream>>>(o_bf, WoE_t, T_e0, scur, T_e1, se0, NTOK, 512);
            gemm_rb<1><<<gFF, 256, 0, stream>>>(T_e1, se0, W1E_t, hid_bf, NTOK, DFF, 512);
            gemm_bb<<<gBB, 256, 0, stream>>>(hid_bf, W2E_t, T_e1, se0, T_e0, se1, NTOK, 2048);
            scur = se1;
        }
    }

    // cross-attn K/V from final encoder state (LN on the fly)
    gemm_rb<3><<<gKV, 256, 0, stream>>>(T_e0, se1, WkvX_t, kvx_bf, NTOK, 1024, 512);

    // -------- decoder --------
    {
        const float* scur = nullptr;
        for (int t = 0; t < DEPTH; t++) {
            const float* trow = time_emb + (size_t)t * DIM;
            fused_attn<1><<<256, 512, 0, stream>>>(T_d0, scur, pos_emb, trow, WqkvD_t, o_bf);
            gemm_bb<<<gBB, 256, 0, stream>>>(o_bf, WoD_t, T_d0, scur, T_d1, sd0, NTOK, 512);

            fused_xattn<<<256, 512, 0, stream>>>(T_d1, sd0, pos_emb, trow, WqX_t, kvx_bf, o_bf);
            gemm_bb<<<gBB, 256, 0, stream>>>(o_bf, WoX_t, T_d1, sd0, T_d2, sd1, NTOK, 512);

            gemm_rb<1><<<gFF, 256, 0, stream>>>(T_d2, sd1, W1D_t, hid_bf, NTOK, DFF, 512);
            gemm_bb<<<gBB, 256, 0, stream>>>(hid_bf, W2D_t, T_d2, sd1, T_d0, sd2, NTOK, 2048);
            scur = sd2;
        }
    }

    // -------- generator + log_softmax (two-pass, XCD-swizzled) --------
    ln_fin<<<NTOK, 64, 0, stream>>>(T_d0, sd2, xd_bf);
    gemm_gen<0><<<dim3(8, 250), 512, 0, stream>>>(xd_bf, Wgen_t, nullptr, pm, psum, nullptr);
    lse_kernel<<<NTOK, 64, 0, stream>>>(pm, psum, lse);
    gemm_gen<1><<<dim3(8, 250), 512, 0, stream>>>(xd_bf, Wgen_t, out, nullptr, nullptr, lse);
}

// Round 16
// 1673.319 us; speedup vs baseline: 1.7547x; 1.0026x over previous
//
#include <hip/hip_runtime.h>
#include <hip/hip_bf16.h>
#include <math.h>

#define H 8
#define DK 64
#define DIM 512
#define DFF 2048
#define DEPTH 8
#define VOCAB 32000
#define NTOK 2048

typedef float f32x4 __attribute__((ext_vector_type(4)));
typedef short bf16x8 __attribute__((ext_vector_type(8)));

static __device__ __forceinline__ unsigned short f2bf(float f) {
    unsigned u = __float_as_uint(f);
    return (unsigned short)((u + 0x7FFFu + ((u >> 16) & 1u)) >> 16);
}

#define GLL(src, dst) __builtin_amdgcn_global_load_lds( \
    (const __attribute__((address_space(1))) unsigned int*)(src), \
    (__attribute__((address_space(3))) unsigned int*)(dst), 16, 0, 0)

// load per-row LN stats (8 partial sum/sumsq pairs) -> mean + inv; identity if stats==null
static __device__ __forceinline__ void load_ln_stats(
    const float* __restrict__ stats, int base, int rows,
    float* Lm, float* Li, int tid, int nthr)
{
    for (int r = tid; r < rows; r += nthr) {
        float m = 0.f, inv = 1.f;
        if (stats) {
            const float* s = stats + (size_t)(base + r) * 16;
            float sum = 0.f, sq = 0.f;
#pragma unroll
            for (int b = 0; b < 8; b++) { sum += s[b * 2]; sq += s[b * 2 + 1]; }
            m = sum * (1.f / 512.f);
            float v = sq * (1.f / 512.f) - m * m;
            inv = 1.f / sqrtf(v + 1e-5f);
        }
        Lm[r] = m; Li[r] = inv;
    }
}

// ---------------- embed ----------------
__global__ void embed_kernel(const float* __restrict__ emb, const int* __restrict__ tok,
                             const float* __restrict__ pos, const int* __restrict__ pidx,
                             float* __restrict__ out, int n4) {
    int idx = blockIdx.x * blockDim.x + threadIdx.x;
    if (idx >= n4) return;
    int i = idx >> 7, d = idx & 127;
    float4 a = ((const float4*)emb)[(size_t)tok[i] * 128 + d];
    float4 b = ((const float4*)pos)[(size_t)pidx[i] * 128 + d];
    ((float4*)out)[idx] = make_float4(a.x + b.x, a.y + b.y, a.z + b.z, a.w + b.w);
}

// ---------------- batched weight convert+transpose ----------------
struct WD { const float* src; unsigned short* dst; int K; int N; int t0; int pad; };
struct WTab { WD d[12]; };

__global__ __launch_bounds__(256) void wconv_all(WTab tab) {
    __shared__ float t[32][33];
    const int bid = blockIdx.x;
    int w = 0;
#pragma unroll
    for (int i = 1; i < 12; i++) if (bid >= tab.d[i].t0) w = i;
    const float* W = tab.d[w].src;
    unsigned short* Wt = tab.d[w].dst;
    const int K = tab.d[w].K, N = tab.d[w].N;
    const int lt = bid - tab.d[w].t0;
    const int txc = N >> 5;
    const int n0 = (lt % txc) << 5, k0 = (lt / txc) << 5;
    const int tid = threadIdx.x;
    const int tx = tid & 31, ty = tid >> 5;
#pragma unroll
    for (int i = 0; i < 32; i += 8)
        t[ty + i][tx] = W[(size_t)(k0 + ty + i) * N + n0 + tx];
    __syncthreads();
#pragma unroll
    for (int i = 0; i < 32; i += 8)
        Wt[(size_t)(n0 + ty + i) * K + k0 + tx] = f2bf(t[tx][ty + i]);
}

// ---------------- gemm_rb: C = LN(T) @ Bt^T, double-buffered ----------------
// EPI 1: relu->bf16; 3: bf16.  BN = 64.
template<int EPI>
__global__ __launch_bounds__(256) void gemm_rb(
    const float* __restrict__ Tf,
    const float* __restrict__ stats,
    const unsigned short* __restrict__ Bt,
    unsigned short* __restrict__ Cb,
    int M, int N, int K)
{
    constexpr int BN = 64, JN = 2;
    __shared__ __align__(16) unsigned short Asm[2][128 * 64];
    __shared__ __align__(16) unsigned short Bsm[2][BN * 64];
    __shared__ float Lm[128], Li[128];
    const int tid = threadIdx.x;
    const int lane = tid & 63, wid = tid >> 6;
    const int m0 = blockIdx.y * 128, n0 = blockIdx.x * BN;
    const int wm = (wid >> 1) * 64, wn = (wid & 1) * (BN / 2);
    const int NK = K >> 6;

    float4 ar0[4], ar1[4];
    auto loadA = [&](int k0) {
#pragma unroll
        for (int it = 0; it < 4; it++) {
            int q = it * 256 + tid;
            int row = q >> 3;
            int cs = q & 7;
            const float* s = Tf + (size_t)(m0 + row) * K + k0 + cs * 8;
            ar0[it] = *(const float4*)s;
            ar1[it] = *(const float4*)(s + 4);
        }
    };
    auto storeA = [&](int buf) {
#pragma unroll
        for (int it = 0; it < 4; it++) {
            int q = it * 256 + tid;
            int row = q >> 3;
            int cs = q & 7;
            float m = Lm[row], iv = Li[row];
            unsigned short c8[8];
            c8[0] = f2bf((ar0[it].x - m) * iv); c8[1] = f2bf((ar0[it].y - m) * iv);
            c8[2] = f2bf((ar0[it].z - m) * iv); c8[3] = f2bf((ar0[it].w - m) * iv);
            c8[4] = f2bf((ar1[it].x - m) * iv); c8[5] = f2bf((ar1[it].y - m) * iv);
            c8[6] = f2bf((ar1[it].z - m) * iv); c8[7] = f2bf((ar1[it].w - m) * iv);
            *(bf16x8*)&Asm[buf][row * 64 + ((cs ^ (row & 7)) * 8)] = *(bf16x8*)c8;
        }
    };
    auto stageB = [&](int k0, int buf) {
#pragma unroll
        for (int it = 0; it < BN / 32; it++) {
            int q = it * 256 + tid;
            int row = q >> 3;
            int cs = (q & 7) ^ (row & 7);
            GLL(Bt + (size_t)(n0 + row) * K + k0 + cs * 8, &Bsm[buf][q * 8]);
        }
    };

    load_ln_stats(stats, m0, 128, Lm, Li, tid, 256);
    loadA(0);
    __syncthreads();
    storeA(0);
    stageB(0, 0);

    f32x4 acc[4][JN];
#pragma unroll
    for (int i = 0; i < 4; i++)
#pragma unroll
        for (int j = 0; j < JN; j++) acc[i][j] = (f32x4){0.f, 0.f, 0.f, 0.f};

    for (int kt = 0; kt < NK; kt++) {
        __syncthreads();
        const int cur = kt & 1, nxt = (kt + 1) & 1;
        if (kt + 1 < NK) {
            stageB((kt + 1) << 6, nxt);
            loadA((kt + 1) << 6);
        }
#pragma unroll
        for (int kk = 0; kk < 2; kk++) {
            bf16x8 af[4], bfr[JN];
#pragma unroll
            for (int i = 0; i < 4; i++) {
                int rowA = wm + i * 16 + (lane & 15);
                int ca = (kk * 4 + (lane >> 4)) ^ (rowA & 7);
                af[i] = *(const bf16x8*)&Asm[cur][rowA * 64 + ca * 8];
            }
#pragma unroll
            for (int j = 0; j < JN; j++) {
                int rowB = wn + j * 16 + (lane & 15);
                int cb = (kk * 4 + (lane >> 4)) ^ (rowB & 7);
                bfr[j] = *(const bf16x8*)&Bsm[cur][rowB * 64 + cb * 8];
            }
#pragma unroll
            for (int i = 0; i < 4; i++)
#pragma unroll
                for (int j = 0; j < JN; j++)
                    acc[i][j] = __builtin_amdgcn_mfma_f32_16x16x32_bf16(af[i], bfr[j], acc[i][j], 0, 0, 0);
        }
        if (kt + 1 < NK) storeA(nxt);
    }
#pragma unroll
    for (int i = 0; i < 4; i++)
#pragma unroll
        for (int j = 0; j < JN; j++)
#pragma unroll
            for (int r = 0; r < 4; r++) {
                int row = m0 + wm + i * 16 + (lane >> 4) * 4 + r;
                int col = n0 + wn + j * 16 + (lane & 15);
                size_t idx = (size_t)row * N + col;
                float v = acc[i][j][r];
                if (EPI == 1) Cb[idx] = f2bf(fmaxf(v, 0.f));
                if (EPI == 3) Cb[idx] = f2bf(v);
            }
}

// ---------------- gemm_bb: Tout = LN(Tin) + A @ Bt^T, double-buffered ----------------
__global__ __launch_bounds__(256) void gemm_bb(
    const unsigned short* __restrict__ A,
    const unsigned short* __restrict__ Bt,
    const float* __restrict__ Tin,
    const float* __restrict__ statsIn,
    float* __restrict__ Tout,
    float* __restrict__ statsOut,
    int M, int K)
{
    __shared__ __align__(16) unsigned short Asm[2][32 * 64];
    __shared__ __align__(16) unsigned short Bsm[2][64 * 64];
    __shared__ float Lm[32], Li[32];
    __shared__ float sredS[4][32], sredQ[4][32];
    const int tid = threadIdx.x;
    const int lane = tid & 63, wid = tid >> 6;
    const int nb = blockIdx.x;
    const int m0 = blockIdx.y * 32, n0 = nb * 64;
    const int wn = wid * 16;
    const int NK = K >> 6;

    auto stage = [&](int k0, int buf) {
        {
            int q = tid;
            int row = q >> 3;
            int cs = (q & 7) ^ (row & 7);
            GLL(A + (size_t)(m0 + row) * K + k0 + cs * 8, &Asm[buf][q * 8]);
        }
#pragma unroll
        for (int it = 0; it < 2; it++) {
            int q = it * 256 + tid;
            int row = q >> 3;
            int cs = (q & 7) ^ (row & 7);
            GLL(Bt + (size_t)(n0 + row) * K + k0 + cs * 8, &Bsm[buf][q * 8]);
        }
    };

    load_ln_stats(statsIn, m0, 32, Lm, Li, tid, 256);
    stage(0, 0);

    f32x4 acc[2];
#pragma unroll
    for (int i = 0; i < 2; i++) acc[i] = (f32x4){0.f, 0.f, 0.f, 0.f};

    for (int kt = 0; kt < NK; kt++) {
        __syncthreads();
        const int cur = kt & 1, nxt = (kt + 1) & 1;
        if (kt + 1 < NK) stage((kt + 1) << 6, nxt);
#pragma unroll
        for (int kd = 0; kd < 2; kd++) {
            int rowB = wn + (lane & 15);
            int cb = (kd * 4 + (lane >> 4)) ^ (rowB & 7);
            bf16x8 bfr = *(const bf16x8*)&Bsm[cur][rowB * 64 + cb * 8];
#pragma unroll
            for (int i = 0; i < 2; i++) {
                int rowA = i * 16 + (lane & 15);
                int ca = (kd * 4 + (lane >> 4)) ^ (rowA & 7);
                bf16x8 af = *(const bf16x8*)&Asm[cur][rowA * 64 + ca * 8];
                acc[i] = __builtin_amdgcn_mfma_f32_16x16x32_bf16(af, bfr, acc[i], 0, 0, 0);
            }
        }
    }
#pragma unroll
    for (int i = 0; i < 2; i++) {
#pragma unroll
        for (int r = 0; r < 4; r++) {
            int rl = i * 16 + (lane >> 4) * 4 + r;
            int row = m0 + rl;
            int col = n0 + wn + (lane & 15);
            size_t idx = (size_t)row * DIM + col;
            float rv = (Tin[idx] - Lm[rl]) * Li[rl];
            float v = acc[i][r] + rv;
            Tout[idx] = v;
            float s = v, q = v * v;
            s += __shfl_xor(s, 1); s += __shfl_xor(s, 2);
            s += __shfl_xor(s, 4); s += __shfl_xor(s, 8);
            q += __shfl_xor(q, 1); q += __shfl_xor(q, 2);
            q += __shfl_xor(q, 4); q += __shfl_xor(q, 8);
            if ((lane & 15) == 0) { sredS[wid][rl] = s; sredQ[wid][rl] = q; }
        }
    }
    __syncthreads();
    if (tid < 32) {
        int row = tid;
        float s = sredS[0][row] + sredS[1][row] + sredS[2][row] + sredS[3][row];
        float q = sredQ[0][row] + sredQ[1][row] + sredQ[2][row] + sredQ[3][row];
        statsOut[(size_t)(m0 + row) * 16 + nb * 2] = s;
        statsOut[(size_t)(m0 + row) * 16 + nb * 2 + 1] = q;
    }
}

// ---------------- attention phase 2: split keys across wave pairs ----------------
template<int CAUSAL>
static __device__ __forceinline__ void attn_phase2_split(
    const unsigned short* Qs, const unsigned short* Ks, const unsigned short* Vt,
    unsigned short* Psw, float* dumpf,
    int qh, int wid, int lane, int tok0, int h,
    unsigned short* __restrict__ O)
{
    const int qg = wid & 3, kh = wid >> 2;
    bf16x8 qa[2];
#pragma unroll
    for (int kd = 0; kd < 2; kd++) {
        int qr = qg * 16 + (lane & 15);
        int ch = (kd * 4 + (lane >> 4)) ^ (qr & 7);
        qa[kd] = *(const bf16x8*)&Qs[qr * 64 + ch * 8];
    }
    int jn, kcn;
    if (!CAUSAL)      { jn = 4; kcn = 2; }
    else if (kh > qh) { jn = 0; kcn = 0; }
    else if (kh < qh) { jn = 4; kcn = 2; }
    else              { kcn = (qg >> 1) + 1; jn = kcn * 2; }

    float zr[4] = {0.f, 0.f, 0.f, 0.f};
    f32x4 oacc[4];
#pragma unroll
    for (int dt = 0; dt < 4; dt++) oacc[dt] = (f32x4){0.f, 0.f, 0.f, 0.f};

    if (jn > 0) {
        f32x4 sacc[4];
#pragma unroll
        for (int j = 0; j < 4; j++) sacc[j] = (f32x4){0.f, 0.f, 0.f, 0.f};
#pragma unroll 2
        for (int kd = 0; kd < 2; kd++) {
            for (int jj = 0; jj < jn; jj++) {
                int kr = kh * 64 + jj * 16 + (lane & 15);
                int ch = (kd * 4 + (lane >> 4)) ^ (kr & 7);
                bf16x8 kf = *(const bf16x8*)&Ks[kr * 64 + ch * 8];
                sacc[jj] = __builtin_amdgcn_mfma_f32_16x16x32_bf16(qa[kd], kf, sacc[jj], 0, 0, 0);
            }
        }
        int qbase = qh * 64 + qg * 16 + (lane >> 4) * 4;
        for (int jj = 0; jj < jn; jj++) {
            int kcol = kh * 64 + jj * 16 + (lane & 15);
#pragma unroll
            for (int rr = 0; rr < 4; rr++) {
                float p = __expf(sacc[jj][rr] * 0.125f);
                if (CAUSAL && kcol > qbase + rr) p = 0.f;
                zr[rr] += p;
                int prow = (lane >> 4) * 4 + rr;
                int ch = ((jj * 2 + ((lane & 15) >> 3)) ^ (prow & 7));
                Psw[prow * 64 + ch * 8 + (lane & 7)] = f2bf(p);
            }
        }
        for (int kcl = 0; kcl < kcn; kcl++) {
            bf16x8 pa;
            {
                int prow = lane & 15;
                int ch = (kcl * 4 + (lane >> 4)) ^ (prow & 7);
                pa = *(const bf16x8*)&Psw[prow * 64 + ch * 8];
            }
            int kcg = kh * 2 + kcl;
#pragma unroll
            for (int dt = 0; dt < 4; dt++) {
                int d = dt * 16 + (lane & 15);
                bf16x8 vf = *(const bf16x8*)&Vt[d * 132 + (kcg * 4 + (lane >> 4)) * 8];
                oacc[dt] = __builtin_amdgcn_mfma_f32_16x16x32_bf16(pa, vf, oacc[dt], 0, 0, 0);
            }
        }
    }
    __syncthreads();
    if (kh == 1) {
        float* dst = dumpf + (size_t)(qg * 64 + lane) * 20;
#pragma unroll
        for (int dt = 0; dt < 4; dt++)
#pragma unroll
            for (int rr = 0; rr < 4; rr++) dst[dt * 4 + rr] = oacc[dt][rr];
#pragma unroll
        for (int rr = 0; rr < 4; rr++) dst[16 + rr] = zr[rr];
    }
    __syncthreads();
    if (kh == 0) {
        const float* src = dumpf + (size_t)(qg * 64 + lane) * 20;
#pragma unroll
        for (int dt = 0; dt < 4; dt++)
#pragma unroll
            for (int rr = 0; rr < 4; rr++) oacc[dt][rr] += src[dt * 4 + rr];
#pragma unroll
        for (int rr = 0; rr < 4; rr++) {
            float z = zr[rr] + src[16 + rr];
            z += __shfl_xor(z, 1); z += __shfl_xor(z, 2);
            z += __shfl_xor(z, 4); z += __shfl_xor(z, 8);
            zr[rr] = 1.f / (z + 1e-9f);
        }
#pragma unroll
        for (int dt = 0; dt < 4; dt++)
#pragma unroll
            for (int rr = 0; rr < 4; rr++) {
                int qrow = tok0 + qh * 64 + qg * 16 + (lane >> 4) * 4 + rr;
                O[(size_t)qrow * DIM + h * 64 + dt * 16 + (lane & 15)] =
                    f2bf(oacc[dt][rr] * zr[rr]);
            }
    }
}

// ---------------- fused QKV-GEMM + self-attention: 256 blocks (b,h,qhalf) ----------------
// Phase-1 double-buffered (A: reg-prefetch + LDS dbuf; B: GLL dbuf); 1 barrier/K-iter.
// Q cols computed only by own-half waves (static branches).
template<int CAUSAL>
__global__ __launch_bounds__(512) void fused_attn(
    const float* __restrict__ Tf,
    const float* __restrict__ stats,
    const float* __restrict__ pos,
    const float* __restrict__ trow,
    const unsigned short* __restrict__ WqkvT,
    unsigned short* __restrict__ O)
{
    __shared__ __align__(16) unsigned short smem[40960];   // 80KB: A 2x8192, B 2x12288
    __shared__ float LmA[128], LiA[128];
    unsigned short* Qs  = smem;             // phase 2 (aliased)
    unsigned short* Ks  = smem + 4096;
    unsigned short* Vt  = smem + 12288;
    float* dumpf = (float*)smem;
    const int tid = threadIdx.x;
    const int lane = tid & 63, wid = tid >> 6;
    unsigned short* Psw = smem + 20736 + wid * 1024;
    const int blk = blockIdx.x;
    const int qh = blk & 1, h = (blk >> 1) & 7, b = blk >> 4;
    const int tok0 = b * 128;
    const int wr = wid * 16;
    const bool own = (wid >> 2) == qh;

    float4 ua[2], ub[2];
    auto loadT = [&](int k0) {
#pragma unroll
        for (int it = 0; it < 2; it++) {
            int q = it * 512 + tid;
            int row = q >> 3;
            int cs = q & 7;
            const float* s = Tf + (size_t)(tok0 + row) * 512 + k0 + cs * 8;
            ua[it] = *(const float4*)s;
            ub[it] = *(const float4*)(s + 4);
        }
    };
    auto storeT = [&](int k0, int buf) {
        unsigned short* Adst = smem + buf * 8192;
#pragma unroll
        for (int it = 0; it < 2; it++) {
            int q = it * 512 + tid;
            int row = q >> 3;
            int cs = q & 7;
            const float* pp = pos + (size_t)row * 512 + k0 + cs * 8;
            const float* tt = trow + k0 + cs * 8;
            float4 p0 = *(const float4*)pp, p1 = *(const float4*)(pp + 4);
            float4 t0 = *(const float4*)tt, t1 = *(const float4*)(tt + 4);
            float m = LmA[row], iv = LiA[row];
            unsigned short c8[8];
            c8[0] = f2bf((ua[it].x - m) * iv + p0.x + t0.x);
            c8[1] = f2bf((ua[it].y - m) * iv + p0.y + t0.y);
            c8[2] = f2bf((ua[it].z - m) * iv + p0.z + t0.z);
            c8[3] = f2bf((ua[it].w - m) * iv + p0.w + t0.w);
            c8[4] = f2bf((ub[it].x - m) * iv + p1.x + t1.x);
            c8[5] = f2bf((ub[it].y - m) * iv + p1.y + t1.y);
            c8[6] = f2bf((ub[it].z - m) * iv + p1.z + t1.z);
            c8[7] = f2bf((ub[it].w - m) * iv + p1.w + t1.w);
            *(bf16x8*)&Adst[row * 64 + ((cs ^ (row & 7)) * 8)] = *(bf16x8*)c8;
        }
    };
    auto stageB = [&](int k0, int buf) {
        unsigned short* Bdst = smem + 16384 + buf * 12288;
#pragma unroll
        for (int it = 0; it < 3; it++) {
            int q = it * 512 + wid * 64 + lane;
            int r = q >> 3;
            int cs = (q & 7) ^ (r & 7);
            int srow = (r < 64) ? (h * 64 + r)
                     : (r < 128) ? (512 + h * 64 + (r - 64))
                                 : (1024 + h * 64 + (r - 128));
            GLL(WqkvT + (size_t)srow * 512 + k0 + cs * 8, &Bdst[(it * 512 + wid * 64) * 8]);
        }
    };

    load_ln_stats(stats, tok0, 128, LmA, LiA, tid, 512);
    loadT(0);
    __syncthreads();       // LmA/LiA visible
    storeT(0, 0);
    stageB(0, 0);

    f32x4 acc[12];
#pragma unroll
    for (int c = 0; c < 12; c++) acc[c] = (f32x4){0.f, 0.f, 0.f, 0.f};

    for (int kt = 0; kt < 8; kt++) {
        __syncthreads();   // buf[cur] ready
        const int cur = kt & 1, nxt = cur ^ 1;
        if (kt < 7) {
            stageB((kt + 1) << 6, nxt);
            loadT((kt + 1) << 6);
        }
        const unsigned short* Acur = smem + cur * 8192;
        const unsigned short* Bcur = smem + 16384 + cur * 12288;
#pragma unroll
        for (int kk = 0; kk < 2; kk++) {
            int rowA = wr + (lane & 15);
            int ca = (kk * 4 + (lane >> 4)) ^ (rowA & 7);
            bf16x8 af = *(const bf16x8*)&Acur[rowA * 64 + ca * 8];
            if (own) {
#pragma unroll
                for (int c = 0; c < 12; c++) {
                    int rowB = c * 16 + (lane & 15);
                    int cb = (kk * 4 + (lane >> 4)) ^ (rowB & 7);
                    bf16x8 bfr = *(const bf16x8*)&Bcur[rowB * 64 + cb * 8];
                    acc[c] = __builtin_amdgcn_mfma_f32_16x16x32_bf16(af, bfr, acc[c], 0, 0, 0);
                }
            } else {
#pragma unroll
                for (int c = 4; c < 12; c++) {
                    int rowB = c * 16 + (lane & 15);
                    int cb = (kk * 4 + (lane >> 4)) ^ (rowB & 7);
                    bf16x8 bfr = *(const bf16x8*)&Bcur[rowB * 64 + cb * 8];
                    acc[c] = __builtin_amdgcn_mfma_f32_16x16x32_bf16(af, bfr, acc[c], 0, 0, 0);
                }
            }
        }
        if (kt < 7) storeT((kt + 1) << 6, nxt);
    }
    __syncthreads();
    // phase 1.5: acc -> LDS (Q own-half only, K/V full)
#pragma unroll
    for (int c = 0; c < 12; c++)
#pragma unroll
        for (int r = 0; r < 4; r++) {
            int token = wr + (lane >> 4) * 4 + r;
            int col = (c & 3) * 16 + (lane & 15);
            unsigned short v = f2bf(acc[c][r]);
            if (c < 4) {
                int tl = token - qh * 64;
                if (tl >= 0 && tl < 64)
                    Qs[tl * 64 + (((col >> 3) ^ (tl & 7)) * 8) + (col & 7)] = v;
            } else if (c < 8) {
                Ks[token * 64 + (((col >> 3) ^ (token & 7)) * 8) + (col & 7)] = v;
            } else {
                Vt[col * 132 + token] = v;
            }
        }
    __syncthreads();
    attn_phase2_split<CAUSAL>(Qs, Ks, Vt, Psw, dumpf, qh, wid, lane, tok0, h, O);
}

// ---------------- fused Q-GEMM + cross-attention: 256 blocks (b,h,qhalf) ----------------
// Phase-1 double-buffered like fused_attn; K/V staged by waves 4-7 up front.
__global__ __launch_bounds__(512) void fused_xattn(
    const float* __restrict__ Tf,
    const float* __restrict__ stats,
    const float* __restrict__ pos,
    const float* __restrict__ trow,
    const unsigned short* __restrict__ WqT,
    const unsigned short* __restrict__ kvx,
    unsigned short* __restrict__ O)
{
    __shared__ __align__(16) unsigned short smem[37120];   // 74.2KB
    __shared__ float LmA[64], LiA[64];
    unsigned short* Qs  = smem;             // [64*64]
    unsigned short* Ks  = smem + 4096;      // [128*64]
    unsigned short* Vt  = smem + 12288;     // [64*132] -> ends 20736
    float* dumpf = (float*)smem;
    const int tid = threadIdx.x;
    const int lane = tid & 63, wid = tid >> 6;
    unsigned short* Psw = smem + 20736 + wid * 1024;       // phase 2 only
    const int blk = blockIdx.x;
    const int qh = blk & 1, h = (blk >> 1) & 7, b = blk >> 4;
    const int tok0 = b * 128;

    float4 ua[2], ub[2];
    auto loadT = [&](int k0) {
#pragma unroll
        for (int it = 0; it < 2; it++) {
            int q = it * 256 + tid;
            int row = q >> 3;
            int cs = q & 7;
            const float* s = Tf + (size_t)(tok0 + qh * 64 + row) * 512 + k0 + cs * 8;
            ua[it] = *(const float4*)s;
            ub[it] = *(const float4*)(s + 4);
        }
    };
    auto storeT = [&](int k0, int buf) {
        unsigned short* Adst = smem + 20736 + buf * 4096;
#pragma unroll
        for (int it = 0; it < 2; it++) {
            int q = it * 256 + tid;
            int row = q >> 3;
            int cs = q & 7;
            const float* pp = pos + (size_t)(qh * 64 + row) * 512 + k0 + cs * 8;
            const float* tt = trow + k0 + cs * 8;
            float4 p0 = *(const float4*)pp, p1 = *(const float4*)(pp + 4);
            float4 t0 = *(const float4*)tt, t1 = *(const float4*)(tt + 4);
            float m = LmA[row], iv = LiA[row];
            unsigned short c8[8];
            c8[0] = f2bf((ua[it].x - m) * iv + p0.x + t0.x);
            c8[1] = f2bf((ua[it].y - m) * iv + p0.y + t0.y);
            c8[2] = f2bf((ua[it].z - m) * iv + p0.z + t0.z);
            c8[3] = f2bf((ua[it].w - m) * iv + p0.w + t0.w);
            c8[4] = f2bf((ub[it].x - m) * iv + p1.x + t1.x);
            c8[5] = f2bf((ub[it].y - m) * iv + p1.y + t1.y);
            c8[6] = f2bf((ub[it].z - m) * iv + p1.z + t1.z);
            c8[7] = f2bf((ub[it].w - m) * iv + p1.w + t1.w);
            *(bf16x8*)&Adst[row * 64 + ((cs ^ (row & 7)) * 8)] = *(bf16x8*)c8;
        }
    };
    auto stageB = [&](int k0, int buf) {
        unsigned short* Bdst = smem + 28928 + buf * 4096;
#pragma unroll
        for (int it = 0; it < 2; it++) {
            int q = it * 256 + tid;
            int r = q >> 3;
            int cs = (q & 7) ^ (r & 7);
            GLL(WqT + (size_t)(h * 64 + r) * 512 + k0 + cs * 8, &Bdst[q * 8]);
        }
    };

    load_ln_stats(stats, tok0 + qh * 64, 64, LmA, LiA, tid, 512);
    if (tid < 256) loadT(0);
    if (wid >= 4) {
        int st = tid - 256;
        int r = st >> 1, c0 = (st & 1) * 4;
        const unsigned short* Kg = kvx + (size_t)(tok0 + r) * 1024 + h * 64;
        const unsigned short* Vg = Kg + 512;
#pragma unroll
        for (int c = c0; c < c0 + 4; c++) {
            bf16x8 kv = *(const bf16x8*)&Kg[c * 8];
            *(bf16x8*)&Ks[r * 64 + ((c ^ (r & 7)) * 8)] = kv;
            bf16x8 vv = *(const bf16x8*)&Vg[c * 8];
#pragma unroll
            for (int j = 0; j < 8; j++)
                Vt[(c * 8 + j) * 132 + r] = (unsigned short)vv[j];
        }
    }
    __syncthreads();       // LmA/LiA + K/V visible
    if (tid < 256) {
        storeT(0, 0);
        stageB(0, 0);
    }

    f32x4 acc[4];
#pragma unroll
    for (int c = 0; c < 4; c++) acc[c] = (f32x4){0.f, 0.f, 0.f, 0.f};

    for (int kt = 0; kt < 8; kt++) {
        __syncthreads();
        const int cur = kt & 1, nxt = cur ^ 1;
        if (tid < 256 && kt < 7) {
            stageB((kt + 1) << 6, nxt);
            loadT((kt + 1) << 6);
        }
        if (wid < 4) {
            const unsigned short* Acur = smem + 20736 + cur * 4096;
            const unsigned short* Bcur = smem + 28928 + cur * 4096;
#pragma unroll
            for (int kk = 0; kk < 2; kk++) {
                int rowA = wid * 16 + (lane & 15);
                int ca = (kk * 4 + (lane >> 4)) ^ (rowA & 7);
                bf16x8 af = *(const bf16x8*)&Acur[rowA * 64 + ca * 8];
#pragma unroll
                for (int c = 0; c < 4; c++) {
                    int rowB = c * 16 + (lane & 15);
                    int cb = (kk * 4 + (lane >> 4)) ^ (rowB & 7);
                    bf16x8 bfr = *(const bf16x8*)&Bcur[rowB * 64 + cb * 8];
                    acc[c] = __builtin_amdgcn_mfma_f32_16x16x32_bf16(af, bfr, acc[c], 0, 0, 0);
                }
            }
        }
        if (tid < 256 && kt < 7) storeT((kt + 1) << 6, nxt);
    }
    __syncthreads();
    if (wid < 4) {
#pragma unroll
        for (int c = 0; c < 4; c++)
#pragma unroll
            for (int r = 0; r < 4; r++) {
                int tl = wid * 16 + (lane >> 4) * 4 + r;
                int col = c * 16 + (lane & 15);
                Qs[tl * 64 + (((col >> 3) ^ (tl & 7)) * 8) + (col & 7)] = f2bf(acc[c][r]);
            }
    }
    __syncthreads();
    attn_phase2_split<0>(Qs, Ks, Vt, Psw, dumpf, qh, wid, lane, tok0, h, O);
}

// ---------------- ln finalize: xb = bf16(LN(T)) using stats ----------------
__global__ __launch_bounds__(64) void ln_fin(const float* __restrict__ T,
                                             const float* __restrict__ stats,
                                             unsigned short* __restrict__ outb) {
    const int row = blockIdx.x, lane = threadIdx.x;
    const float* st = stats + (size_t)row * 16;
    float sum = 0.f, sq = 0.f;
#pragma unroll
    for (int b = 0; b < 8; b++) { sum += st[b * 2]; sq += st[b * 2 + 1]; }
    float m = sum * (1.f / 512.f);
    float v = sq * (1.f / 512.f) - m * m;
    float inv = 1.f / sqrtf(v + 1e-5f);
    const float* p = T + (size_t)row * DIM;
    unsigned short* qb = outb + (size_t)row * DIM;
#pragma unroll
    for (int i = 0; i < 8; i++)
        qb[lane + i * 64] = f2bf((p[lane + i * 64] - m) * inv);
}

// ---------------- generator: 256x128 tile, XCD-swizzled, two-pass ----------------
template<int PASS>
__global__ __launch_bounds__(512) void gemm_gen(
    const unsigned short* __restrict__ Ab,
    const unsigned short* __restrict__ Bt,
    float* __restrict__ Out,
    float* __restrict__ pm,
    float* __restrict__ psum,
    const float* __restrict__ lse)
{
    __shared__ __align__(16) unsigned short Asm[256 * 64];
    __shared__ __align__(16) unsigned short Bsm[128 * 64];
    __shared__ float pml[8][64];
    __shared__ float psl[8][64];
    __shared__ float lsh[256];
    const int tid = threadIdx.x;
    const int lane = tid & 63, wid = tid >> 6;
    const int d = blockIdx.x + blockIdx.y * 8;
    const int t = (d & 7) * 250 + (d >> 3);
    const int mt = t & 7, nt = t >> 3;
    const int m0 = mt * 256, n0 = nt * 128;
    const int wm = (wid >> 1) * 64, wn = (wid & 1) * 64;

    if (PASS == 1) {
        for (int r = tid; r < 256; r += 512) lsh[r] = lse[m0 + r];
        __syncthreads();
    }

    f32x4 acc[4][4];
#pragma unroll
    for (int i = 0; i < 4; i++)
#pragma unroll
        for (int j = 0; j < 4; j++) acc[i][j] = (f32x4){0.f, 0.f, 0.f, 0.f};

    for (int k0 = 0; k0 < 512; k0 += 64) {
        if (k0 || PASS == 1) __syncthreads();
#pragma unroll
        for (int it = 0; it < 2; it++) {
            int q = it * 512 + tid;
            int row = q >> 3;
            int cs = (q & 7) ^ (row & 7);
            GLL(Bt + (size_t)(n0 + row) * 512 + k0 + cs * 8, &Bsm[(it * 512 + wid * 64) * 8]);
        }
#pragma unroll
        for (int it = 0; it < 4; it++) {
            int q = it * 512 + tid;
            int row = q >> 3;
            int cs = (q & 7) ^ (row & 7);
            GLL(Ab + (size_t)(m0 + row) * 512 + k0 + cs * 8, &Asm[(it * 512 + wid * 64) * 8]);
        }
        __syncthreads();
#pragma unroll
        for (int kk = 0; kk < 2; kk++) {
            bf16x8 af[4], bfr[4];
#pragma unroll
            for (int i = 0; i < 4; i++) {
                int rowA = wm + i * 16 + (lane & 15);
                int ca = (kk * 4 + (lane >> 4)) ^ (rowA & 7);
                af[i] = *(const bf16x8*)&Asm[rowA * 64 + ca * 8];
                int rowB = wn + i * 16 + (lane & 15);
                int cb = (kk * 4 + (lane >> 4)) ^ (rowB & 7);
                bfr[i] = *(const bf16x8*)&Bsm[rowB * 64 + cb * 8];
            }
#pragma unroll
            for (int i = 0; i < 4; i++)
#pragma unroll
                for (int j = 0; j < 4; j++)
                    acc[i][j] = __builtin_amdgcn_mfma_f32_16x16x32_bf16(af[i], bfr[j], acc[i][j], 0, 0, 0);
        }
    }
    if (PASS == 0) {
#pragma unroll
        for (int i = 0; i < 4; i++) {
#pragma unroll
            for (int r = 0; r < 4; r++) {
                float mx = fmaxf(fmaxf(acc[i][0][r], acc[i][1][r]),
                                 fmaxf(acc[i][2][r], acc[i][3][r]));
                mx = fmaxf(mx, __shfl_xor(mx, 1));
                mx = fmaxf(mx, __shfl_xor(mx, 2));
                mx = fmaxf(mx, __shfl_xor(mx, 4));
                mx = fmaxf(mx, __shfl_xor(mx, 8));
                float s = __expf(acc[i][0][r] - mx) + __expf(acc[i][1][r] - mx) +
                          __expf(acc[i][2][r] - mx) + __expf(acc[i][3][r] - mx);
                s += __shfl_xor(s, 1); s += __shfl_xor(s, 2);
                s += __shfl_xor(s, 4); s += __shfl_xor(s, 8);
                if ((lane & 15) == 0) {
                    int li = i * 16 + (lane >> 4) * 4 + r;
                    pml[wid][li] = mx;
                    psl[wid][li] = s;
                }
            }
        }
        __syncthreads();
        if (tid < 256) {
            int g = tid >> 6, lr = tid & 63;
            int wa = g * 2, wb = g * 2 + 1;
            float m = fmaxf(pml[wa][lr], pml[wb][lr]);
            float s = psl[wa][lr] * __expf(pml[wa][lr] - m) + psl[wb][lr] * __expf(pml[wb][lr] - m);
            pm[(size_t)(m0 + g * 64 + lr) * 256 + nt] = m;
            psum[(size_t)(m0 + g * 64 + lr) * 256 + nt] = s;
        }
    } else {
#pragma unroll
        for (int i = 0; i < 4; i++)
#pragma unroll
            for (int j = 0; j < 4; j++)
#pragma unroll
                for (int r = 0; r < 4; r++) {
                    int rl = wm + i * 16 + (lane >> 4) * 4 + r;
                    int col = n0 + wn + j * 16 + (lane & 15);
                    Out[(size_t)(m0 + rl) * VOCAB + col] = acc[i][j][r] - lsh[rl];
                }
    }
}

// ---------------- lse reduce ----------------
__global__ __launch_bounds__(64) void lse_kernel(const float* __restrict__ pm,
                                                 const float* __restrict__ psum,
                                                 float* __restrict__ lse) {
    const int row = blockIdx.x, t = threadIdx.x;
    float m = -1e30f, s = 0.f;
    for (int nb = t; nb < 250; nb += 64) {
        float mm = pm[(size_t)row * 256 + nb];
        float ss = psum[(size_t)row * 256 + nb];
        float M = fmaxf(m, mm);
        s = s * __expf(m - M) + ss * __expf(mm - M);
        m = M;
    }
#pragma unroll
    for (int off = 32; off > 0; off >>= 1) {
        float mo = __shfl_xor(m, off), so = __shfl_xor(s, off);
        float M = fmaxf(m, mo);
        s = s * __expf(m - M) + so * __expf(mo - M);
        m = M;
    }
    if (t == 0) lse[row] = m + __logf(s);
}

// ---------------- orchestration ----------------
extern "C" void kernel_launch(void* const* d_in, const int* in_sizes, int n_in,
                              void* d_out, int out_size, void* d_ws, size_t ws_size,
                              hipStream_t stream) {
    const float* emb_src  = (const float*)d_in[0];
    const float* emb_tgt  = (const float*)d_in[1];
    const float* pos_emb  = (const float*)d_in[2];
    const float* time_emb = (const float*)d_in[3];
    const float* Wqkv_e   = (const float*)d_in[4];
    const float* Wo_e     = (const float*)d_in[5];
    const float* W1_e     = (const float*)d_in[6];
    const float* W2_e     = (const float*)d_in[7];
    const float* Wqkv_d   = (const float*)d_in[8];
    const float* Wo_d     = (const float*)d_in[9];
    const float* W1_d     = (const float*)d_in[10];
    const float* W2_d     = (const float*)d_in[11];
    const float* Wq_x     = (const float*)d_in[12];
    const float* Wkv_x    = (const float*)d_in[13];
    const float* Wo_x     = (const float*)d_in[14];
    const float* Wgen     = (const float*)d_in[15];
    const int* src_tokens = (const int*)d_in[16];
    const int* tgt_tokens = (const int*)d_in[17];
    const int* src_pos    = (const int*)d_in[18];
    const int* tgt_pos    = (const int*)d_in[19];

    char* w = (char*)d_ws;
    float* T_e0 = (float*)(w);
    float* T_e1 = (float*)(w + (4u << 20));
    float* T_d0 = (float*)(w + (8u << 20));
    float* T_d1 = (float*)(w + (12u << 20));
    float* T_d2 = (float*)(w + (16u << 20));
    unsigned short* kvx_bf = (unsigned short*)(w + (20u << 20));
    unsigned short* o_bf   = (unsigned short*)(w + (24u << 20));
    unsigned short* hid_bf = (unsigned short*)(w + (26u << 20));
    unsigned short* xd_bf  = (unsigned short*)(w + (34u << 20));
    float* pm   = (float*)(w + (36u << 20));
    float* psum = (float*)(w + (38u << 20));
    float* se0  = (float*)(w + (40u << 20));
    float* se1  = se0 + 32768;
    float* sd0  = se1 + 32768;
    float* sd1  = sd0 + 32768;
    float* sd2  = sd1 + 32768;
    float* lse  = sd2 + 32768;
    unsigned short* wts = (unsigned short*)(w + (41u << 20));

    unsigned short* WqkvE_t = wts;
    unsigned short* WoE_t   = WqkvE_t + 786432;
    unsigned short* W1E_t   = WoE_t   + 262144;
    unsigned short* W2E_t   = W1E_t   + 1048576;
    unsigned short* WqkvD_t = W2E_t   + 1048576;
    unsigned short* WoD_t   = WqkvD_t + 786432;
    unsigned short* W1D_t   = WoD_t   + 262144;
    unsigned short* W2D_t   = W1D_t   + 1048576;
    unsigned short* WqX_t   = W2D_t   + 1048576;
    unsigned short* WkvX_t  = WqX_t   + 262144;
    unsigned short* WoX_t   = WkvX_t  + 524288;
    unsigned short* Wgen_t  = WoX_t   + 262144;

    float* out = (float*)d_out;

    WTab tab;
    auto set = [&](int i, const float* s, unsigned short* d, int K, int N, int t0) {
        tab.d[i].src = s; tab.d[i].dst = d; tab.d[i].K = K; tab.d[i].N = N;
        tab.d[i].t0 = t0; tab.d[i].pad = 0;
    };
    set(0,  Wqkv_e, WqkvE_t, 512, 1536, 0);
    set(1,  Wo_e,   WoE_t,   512, 512,  768);
    set(2,  W1_e,   W1E_t,   512, 2048, 1024);
    set(3,  W2_e,   W2E_t,   2048, 512, 2048);
    set(4,  Wqkv_d, WqkvD_t, 512, 1536, 3072);
    set(5,  Wo_d,   WoD_t,   512, 512,  3840);
    set(6,  W1_d,   W1D_t,   512, 2048, 4096);
    set(7,  W2_d,   W2D_t,   2048, 512, 5120);
    set(8,  Wq_x,   WqX_t,   512, 512,  6144);
    set(9,  Wkv_x,  WkvX_t,  512, 1024, 6400);
    set(10, Wo_x,   WoX_t,   512, 512,  6912);
    set(11, Wgen,   Wgen_t,  512, 32000, 7168);
    wconv_all<<<23168, 256, 0, stream>>>(tab);

    const int n4 = NTOK * (DIM / 4);
    dim3 eb(256), eg((n4 + 255) / 256);
    embed_kernel<<<eg, eb, 0, stream>>>(emb_src, src_tokens, pos_emb, src_pos, T_e0, n4);
    embed_kernel<<<eg, eb, 0, stream>>>(emb_tgt, tgt_tokens, pos_emb, tgt_pos, T_d0, n4);

    const dim3 gFF(DFF / 64, NTOK / 128),
               gKV(1024 / 64, NTOK / 128),
               gBB(8, NTOK / 32);

    // -------- encoder --------
    {
        const float* scur = nullptr;
        for (int t = 0; t < DEPTH; t++) {
            const float* trow = time_emb + (size_t)t * DIM;
            fused_attn<0><<<256, 512, 0, stream>>>(T_e0, scur, pos_emb, trow, WqkvE_t, o_bf);
            gemm_bb<<<gBB, 256, 0, stream>>>(o_bf, WoE_t, T_e0, scur, T_e1, se0, NTOK, 512);
            gemm_rb<1><<<gFF, 256, 0, stream>>>(T_e1, se0, W1E_t, hid_bf, NTOK, DFF, 512);
            gemm_bb<<<gBB, 256, 0, stream>>>(hid_bf, W2E_t, T_e1, se0, T_e0, se1, NTOK, 2048);
            scur = se1;
        }
    }

    // cross-attn K/V from final encoder state (LN on the fly)
    gemm_rb<3><<<gKV, 256, 0, stream>>>(T_e0, se1, WkvX_t, kvx_bf, NTOK, 1024, 512);

    // -------- decoder --------
    {
        const float* scur = nullptr;
        for (int t = 0; t < DEPTH; t++) {
            const float* trow = time_emb + (size_t)t * DIM;
            fused_attn<1><<<256, 512, 0, stream>>>(T_d0, scur, pos_emb, trow, WqkvD_t, o_bf);
            gemm_bb<<<gBB, 256, 0, stream>>>(o_bf, WoD_t, T_d0, scur, T_d1, sd0, NTOK, 512);

            fused_xattn<<<256, 512, 0, stream>>>(T_d1, sd0, pos_emb, trow, WqX_t, kvx_bf, o_bf);
            gemm_bb<<<gBB, 256, 0, stream>>>(o_bf, WoX_t, T_d1, sd0, T_d2, sd1, NTOK, 512);

            gemm_rb<1><<<gFF, 256, 0, stream>>>(T_d2, sd1, W1D_t, hid_bf, NTOK, DFF, 512);
            gemm_bb<<<gBB, 256, 0, stream>>>(hid_bf, W2D_t, T_d2, sd1, T_d0, sd2, NTOK, 2048);
            scur = sd2;
        }
    }

    // -------- generator + log_softmax (two-pass, XCD-swizzled) --------
    ln_fin<<<NTOK, 64, 0, stream>>>(T_d0, sd2, xd_bf);
    gemm_gen<0><<<dim3(8, 250), 512, 0, stream>>>(xd_bf, Wgen_t, nullptr, pm, psum, nullptr);
    lse_kernel<<<NTOK, 64, 0, stream>>>(pm, psum, lse);
    gemm_gen<1><<<dim3(8, 250), 512, 0, stream>>>(xd_bf, Wgen_t, out, nullptr, nullptr, lse);
}